// Round 4
// baseline (898.190 us; speedup 1.0000x reference)
//
#pragma clang fp contract(off)
#include <hip/hip_runtime.h>
#include <math.h>

#define N_PTS   4096
#define B_SZ    8
#define NPOINT  1024
#define NSAMPLE 32
#define C_FEAT  128
#define C_IN    131
#define C_OUT   256
#define R2      1e-2f   // float(0.1*0.1) as JAX weak-casts it

#define KT      5       // K tiles of 32 (131 -> 160 padded)
#define NT      16      // N tiles of 16 (256)
#define KPAD    168     // LDS row stride in bf16 elems

typedef __attribute__((ext_vector_type(8))) short bf16x8;
typedef __attribute__((ext_vector_type(4))) float f32x4;
typedef __attribute__((ext_vector_type(2))) float v2f;

__device__ __forceinline__ unsigned short f2bf(float f) {   // RNE, matches hw cvt
    unsigned u = __float_as_uint(f);
    return (unsigned short)((u + 0x7FFF + ((u >> 16) & 1)) >> 16);
}
__device__ __forceinline__ float bf2f(unsigned short h) {
    return __uint_as_float(((unsigned)h) << 16);
}

// ---------------- K0: split W into bf16 hi/lo, pre-swizzled into MFMA B-fragment order ----
__global__ __launch_bounds__(64) void k_wtrans(const float* __restrict__ W,
                                               unsigned short* __restrict__ Wb_hi,
                                               unsigned short* __restrict__ Wb_lo) {
    const int blk  = blockIdx.x;            // kt*NT + nt
    const int kt   = blk / NT, nt = blk % NT;
    const int lane = threadIdx.x;
    const int o    = nt * 16 + (lane & 15);
    const int k0   = kt * 32 + (lane >> 4) * 8;
    const size_t base = ((size_t)blk * 64 + lane) * 8;
#pragma unroll
    for (int j = 0; j < 8; ++j) {
        int k = k0 + j;
        float v = 0.0f;
        if (k < C_IN) {
            int src = (k < C_FEAT) ? (k + 3) : (k - C_FEAT);
            v = W[o * C_IN + src];
        }
        unsigned short hh = f2bf(v);
        Wb_hi[base + j] = hh;
        Wb_lo[base + j] = f2bf(v - bf2f(hh));
    }
}

// ---------------- K1: furthest point sampling (packed-math v3) ----------------
#define FPS_BLOCK 512
#define FPS_PPT   8     // 4 float2 pairs per thread

#define DPP_IMAX(x, ctrl, rmask)                                              \
    do {                                                                      \
        int _y = __builtin_amdgcn_update_dpp(x, x, ctrl, rmask, 0xf, false);  \
        x = (_y > x) ? _y : x;                                                \
    } while (0)

__global__ __launch_bounds__(FPS_BLOCK) void k_fps(const float* __restrict__ xyz,
                                                   float* __restrict__ new_xyz) {
    const int b    = blockIdx.x;
    const int t    = threadIdx.x;
    const int lane = t & 63;
    const int wid  = t >> 6;
    __shared__ float xl[N_PTS], yl[N_PTS], zl[N_PTS];
    __shared__ unsigned long long red[2][FPS_BLOCK / 64];

    const float* base = xyz + (size_t)b * N_PTS * 3;

    // pairs: X[p] = {x(2p), x(2p+1)} for this thread's 8 points
    v2f X[4], Y[4], Z[4], M[4];

    const float4* b4 = (const float4*)(base + (size_t)t * (FPS_PPT * 3));
    float4 v[6];
#pragma unroll
    for (int i = 0; i < 6; ++i) v[i] = b4[i];
    const float* vf = (const float*)v;
#pragma unroll
    for (int p = 0; p < 4; ++p) {
        X[p] = (v2f){vf[(2 * p) * 3 + 0], vf[(2 * p + 1) * 3 + 0]};
        Y[p] = (v2f){vf[(2 * p) * 3 + 1], vf[(2 * p + 1) * 3 + 1]};
        Z[p] = (v2f){vf[(2 * p) * 3 + 2], vf[(2 * p + 1) * 3 + 2]};
        M[p] = (v2f){1e10f, 1e10f};
        int gi = t * FPS_PPT + 2 * p;
        xl[gi] = X[p].x; xl[gi + 1] = X[p].y;
        yl[gi] = Y[p].x; yl[gi + 1] = Y[p].y;
        zl[gi] = Z[p].x; zl[gi + 1] = Z[p].y;
    }
    __syncthreads();

    float cx = xl[0], cy = yl[0], cz = zl[0];
    if (t == 0) {
        float* o = new_xyz + (size_t)b * NPOINT * 3;
        o[0] = cx; o[1] = cy; o[2] = cz;
    }

    for (int it = 1; it < NPOINT; ++it) {
        // ---- packed distance update: v_pk_{add,mul,min}_f32 ----
#pragma unroll
        for (int p = 0; p < 4; ++p) {
            v2f dx = X[p] - cx;
            v2f dy = Y[p] - cy;
            v2f dz = Z[p] - cz;
            v2f d  = ((dx * dx) + (dy * dy)) + (dz * dz);  // contract(off): no FMA
            M[p]   = __builtin_elementwise_min(M[p], d);
        }
        // ---- local max (no index tracking), then wave DPP argmax ----
        v2f m01 = __builtin_elementwise_max(M[0], M[1]);
        v2f m23 = __builtin_elementwise_max(M[2], M[3]);
        v2f mp  = __builtin_elementwise_max(m01, m23);
        const float bestv = fmaxf(mp.x, mp.y);
        const int bb = __float_as_int(bestv);       // >=0: int order == float order
        int r = bb;
        DPP_IMAX(r, 0x111, 0xf);
        DPP_IMAX(r, 0x112, 0xf);
        DPP_IMAX(r, 0x114, 0xf);
        DPP_IMAX(r, 0x118, 0xf);
        DPP_IMAX(r, 0x142, 0xa);
        DPP_IMAX(r, 0x143, 0xc);
        const int vmax = __builtin_amdgcn_readlane(r, 63);
        const unsigned long long em = __ballot(bb == vmax);
        const int l = __ffsll((unsigned long long)em) - 1;  // lowest lane = lowest base idx
        // ---- winner lane only: recover local j (lowest => lowest global idx) ----
        if (lane == l) {
            unsigned mm = 0;
#pragma unroll
            for (int p = 0; p < 4; ++p) {
                if (__float_as_int(M[p].x) == vmax) mm |= 1u << (2 * p);
                if (__float_as_int(M[p].y) == vmax) mm |= 1u << (2 * p + 1);
            }
            const int j    = __ffs(mm) - 1;
            const int gidx = t * FPS_PPT + j;
            red[it & 1][wid] = ((unsigned long long)(unsigned)vmax << 32)
                             | (unsigned)(N_PTS - 1 - gidx);
        }
        __syncthreads();
        // ---- cross-wave: 3-level tree over the 8 keys ----
        const unsigned long long* rp = red[it & 1];
        unsigned long long k0 = rp[0], k1 = rp[1], k2 = rp[2], k3 = rp[3];
        unsigned long long k4 = rp[4], k5 = rp[5], k6 = rp[6], k7 = rp[7];
        unsigned long long b01 = k0 > k1 ? k0 : k1;
        unsigned long long b23 = k2 > k3 ? k2 : k3;
        unsigned long long b45 = k4 > k5 ? k4 : k5;
        unsigned long long b67 = k6 > k7 ? k6 : k7;
        unsigned long long b03 = b01 > b23 ? b01 : b23;
        unsigned long long b47 = b45 > b67 ? b45 : b67;
        unsigned long long best = b03 > b47 ? b03 : b47;
        const int idx = N_PTS - 1 - (int)(best & 0xFFFFull);
        cx = xl[idx]; cy = yl[idx]; cz = zl[idx];
        if (t == 0) {
            float* o = new_xyz + ((size_t)b * NPOINT + it) * 3;
            o[0] = cx; o[1] = cy; o[2] = cz;
        }
    }
}

// ---------------- K2: ball query (unchanged) ----------------
__global__ __launch_bounds__(256) void k_ballquery(const float* __restrict__ xyz,
                                                   const float* __restrict__ new_xyz,
                                                   int* __restrict__ out_idx) {
    const int lane = threadIdx.x & 63;
    const int wid  = threadIdx.x >> 6;
    const int b    = blockIdx.y;
    const int s    = blockIdx.x * 4 + wid;

    const float* xb = xyz + (size_t)b * N_PTS * 3;
    const float* q  = new_xyz + ((size_t)b * NPOINT + s) * 3;
    float qx = q[0], qy = q[1], qz = q[2];
    int* ob = out_idx + ((size_t)b * NPOINT + s) * NSAMPLE;

    int total = 0, first = -1;
    const unsigned long long mlt = (1ull << lane) - 1ull;

    for (int ch = 0; ch < N_PTS / 64; ++ch) {
        int i = ch * 64 + lane;
        float x = xb[i * 3 + 0], y = xb[i * 3 + 1], z = xb[i * 3 + 2];
        float dx = qx - x, dy = qy - y, dz = qz - z;
        float d2 = ((dx * dx) + (dy * dy)) + (dz * dz);
        bool valid = d2 < R2;
        unsigned long long m = __ballot(valid);
        if (valid) {
            int pos = total + __popcll(m & mlt);
            if (pos < NSAMPLE) ob[pos] = i;
        }
        if (first < 0 && m != 0ull) first = ch * 64 + (__ffsll(m) - 1);
        total += __popcll(m);
        if (total >= NSAMPLE) break;
    }
    if (total < NSAMPLE) {
        if (lane >= total && lane < NSAMPLE) ob[lane] = first;
    }
}

// ---------------- K3: gather + BN + ReLU + split-bf16 MFMA GEMM + max ----------------
__device__ __forceinline__ float bn_relu(float v, float mean, float scale, float beta) {
    float r = ((v - mean) * scale) + beta;
    return fmaxf(r, 0.0f);
}

__global__ __launch_bounds__(256) void k_group_gemm(
    const float* __restrict__ xyz, const float* __restrict__ feat,
    const float* __restrict__ new_xyz, const int* __restrict__ idx,
    const unsigned short* __restrict__ Wb_hi, const unsigned short* __restrict__ Wb_lo,
    const float* __restrict__ bias,
    const float* __restrict__ bn_g, const float* __restrict__ bn_b,
    const float* __restrict__ bn_m, const float* __restrict__ bn_v,
    float* __restrict__ out) {
    const int sx = blockIdx.x;
    const int s  = ((sx & 7) << 7) | (sx >> 3);   // 128-long contiguous s-runs per XCD
    const int b  = blockIdx.y;
    const int t  = threadIdx.x;
    const int lane = t & 63;
    const int w    = t >> 6;

    __shared__ unsigned short Xh[32][KPAD], Xl[32][KPAD];
    __shared__ float sc_l[C_IN], mn_l[C_IN], bt_l[C_IN];
    __shared__ int   idxs[NSAMPLE];
    __shared__ float nq[3];

    if (t < C_IN) {
        float g  = bn_g[t];
        float vv = bn_v[t] + 1e-5f;
        sc_l[t] = g / sqrtf(vv);
        mn_l[t] = bn_m[t];
        bt_l[t] = bn_b[t];
    }
    if (t < NSAMPLE) idxs[t] = idx[((size_t)b * NPOINT + s) * NSAMPLE + t];
    if (t < 3)       nq[t]   = new_xyz[((size_t)b * NPOINT + s) * 3 + t];
    __syncthreads();

    {
        const int ks = t & 31;
        const int qh = t >> 5;
        const float* frow = feat + ((size_t)b * N_PTS + idxs[ks]) * C_FEAT;
#pragma unroll
        for (int m = 0; m < 4; ++m) {
            int qq = m * 8 + qh;
            int c0 = qq * 4;
            float4 f = *(const float4*)&frow[c0];
            float v0 = bn_relu(f.x, mn_l[3 + c0 + 0], sc_l[3 + c0 + 0], bt_l[3 + c0 + 0]);
            float v1 = bn_relu(f.y, mn_l[3 + c0 + 1], sc_l[3 + c0 + 1], bt_l[3 + c0 + 1]);
            float v2 = bn_relu(f.z, mn_l[3 + c0 + 2], sc_l[3 + c0 + 2], bt_l[3 + c0 + 2]);
            float v3 = bn_relu(f.w, mn_l[3 + c0 + 3], sc_l[3 + c0 + 3], bt_l[3 + c0 + 3]);
            unsigned short h0 = f2bf(v0), h1 = f2bf(v1), h2 = f2bf(v2), h3 = f2bf(v3);
            uint2 hv, lv;
            hv.x = (unsigned)h0 | ((unsigned)h1 << 16);
            hv.y = (unsigned)h2 | ((unsigned)h3 << 16);
            lv.x = (unsigned)f2bf(v0 - bf2f(h0)) | ((unsigned)f2bf(v1 - bf2f(h1)) << 16);
            lv.y = (unsigned)f2bf(v2 - bf2f(h2)) | ((unsigned)f2bf(v3 - bf2f(h3)) << 16);
            *(uint2*)&Xh[ks][c0] = hv;
            *(uint2*)&Xl[ks][c0] = lv;
        }
    }
    if (t < 32) {
        const int row = t;
        const int id  = idxs[row];
        const float* p = xyz + ((size_t)b * N_PTS + id) * 3;
        uint4 z4 = {0u, 0u, 0u, 0u};
        uint4 hh = z4, ll = z4;
        unsigned short h[3];
#pragma unroll
        for (int d = 0; d < 3; ++d) {
            float g = p[d] - nq[d];
            float v = bn_relu(g, mn_l[d], sc_l[d], bt_l[d]);
            h[d] = f2bf(v);
            unsigned short lo = f2bf(v - bf2f(h[d]));
            if (d == 0) { hh.x |= h[d];                 ll.x |= lo; }
            if (d == 1) { hh.x |= (unsigned)h[d] << 16; ll.x |= (unsigned)lo << 16; }
            if (d == 2) { hh.y |= h[d];                 ll.y |= lo; }
        }
        *(uint4*)&Xh[row][128] = hh;  *(uint4*)&Xl[row][128] = ll;
        *(uint4*)&Xh[row][136] = z4;  *(uint4*)&Xl[row][136] = z4;
        *(uint4*)&Xh[row][144] = z4;  *(uint4*)&Xl[row][144] = z4;
        *(uint4*)&Xh[row][152] = z4;  *(uint4*)&Xl[row][152] = z4;
        *(uint4*)&Xh[row][160] = z4;  *(uint4*)&Xl[row][160] = z4;
    }
    __syncthreads();

    f32x4 zero = {0.f, 0.f, 0.f, 0.f};
    f32x4 acc[2][4];
#pragma unroll
    for (int m = 0; m < 2; ++m)
#pragma unroll
        for (int n = 0; n < 4; ++n) acc[m][n] = zero;

    const int r0 = lane & 15;
#pragma unroll
    for (int kt = 0; kt < KT; ++kt) {
        const int k0 = kt * 32 + (lane >> 4) * 8;
        bf16x8 a0h = *(const bf16x8*)&Xh[r0][k0];
        bf16x8 a1h = *(const bf16x8*)&Xh[16 + r0][k0];
        bf16x8 a0l = *(const bf16x8*)&Xl[r0][k0];
        bf16x8 a1l = *(const bf16x8*)&Xl[16 + r0][k0];
#pragma unroll
        for (int n = 0; n < 4; ++n) {
            const int nt = w * 4 + n;
            const size_t off = (((size_t)kt * NT + nt) * 64 + lane) * 8;
            bf16x8 bh = *(const bf16x8*)&Wb_hi[off];
            bf16x8 bl = *(const bf16x8*)&Wb_lo[off];
            acc[0][n] = __builtin_amdgcn_mfma_f32_16x16x32_bf16(a0h, bh, acc[0][n], 0, 0, 0);
            acc[1][n] = __builtin_amdgcn_mfma_f32_16x16x32_bf16(a1h, bh, acc[1][n], 0, 0, 0);
            acc[0][n] = __builtin_amdgcn_mfma_f32_16x16x32_bf16(a0l, bh, acc[0][n], 0, 0, 0);
            acc[1][n] = __builtin_amdgcn_mfma_f32_16x16x32_bf16(a1l, bh, acc[1][n], 0, 0, 0);
            acc[0][n] = __builtin_amdgcn_mfma_f32_16x16x32_bf16(a0h, bl, acc[0][n], 0, 0, 0);
            acc[1][n] = __builtin_amdgcn_mfma_f32_16x16x32_bf16(a1h, bl, acc[1][n], 0, 0, 0);
        }
    }

#pragma unroll
    for (int n = 0; n < 4; ++n) {
        float m0 = fmaxf(acc[0][n][0], acc[1][n][0]);
        float m1 = fmaxf(acc[0][n][1], acc[1][n][1]);
        float m2 = fmaxf(acc[0][n][2], acc[1][n][2]);
        float m3 = fmaxf(acc[0][n][3], acc[1][n][3]);
        float pm = fmaxf(fmaxf(m0, m1), fmaxf(m2, m3));
        pm = fmaxf(pm, __shfl_xor(pm, 16));
        pm = fmaxf(pm, __shfl_xor(pm, 32));
        if (lane < 16) {
            int o = (w * 4 + n) * 16 + lane;
            out[(size_t)b * C_OUT * NPOINT + (size_t)o * NPOINT + s] = pm + bias[o];
        }
    }
}

extern "C" void kernel_launch(void* const* d_in, const int* in_sizes, int n_in,
                              void* d_out, int out_size, void* d_ws, size_t ws_size,
                              hipStream_t stream) {
    const float* xyz  = (const float*)d_in[0];
    const float* feat = (const float*)d_in[1];
    const float* W    = (const float*)d_in[2];
    const float* bias = (const float*)d_in[3];
    const float* bn_g = (const float*)d_in[4];
    const float* bn_b = (const float*)d_in[5];
    const float* bn_m = (const float*)d_in[6];
    const float* bn_v = (const float*)d_in[7];

    float* new_xyz  = (float*)d_out;                                   // (8,1024,3)
    float* out_feat = (float*)d_out + (size_t)B_SZ * NPOINT * 3;       // (8,256,1024)

    int*            ws_idx = (int*)d_ws;
    unsigned short* Wb_hi  = (unsigned short*)((char*)d_ws + (size_t)B_SZ * NPOINT * NSAMPLE * sizeof(int));
    unsigned short* Wb_lo  = Wb_hi + (size_t)KT * NT * 64 * 8;

    hipLaunchKernelGGL(k_wtrans, dim3(KT * NT), dim3(64), 0, stream, W, Wb_hi, Wb_lo);
    hipLaunchKernelGGL(k_fps, dim3(B_SZ), dim3(FPS_BLOCK), 0, stream, xyz, new_xyz);
    hipLaunchKernelGGL(k_ballquery, dim3(NPOINT / 4, B_SZ), dim3(256), 0, stream,
                       xyz, new_xyz, ws_idx);
    hipLaunchKernelGGL(k_group_gemm, dim3(NPOINT, B_SZ), dim3(256), 0, stream,
                       xyz, feat, new_xyz, ws_idx, Wb_hi, Wb_lo, bias,
                       bn_g, bn_b, bn_m, bn_v, out_feat);
}

// Round 5
// 874.330 us; speedup vs baseline: 1.0273x; 1.0273x over previous
//
#pragma clang fp contract(off)
#include <hip/hip_runtime.h>
#include <math.h>

#define N_PTS   4096
#define B_SZ    8
#define NPOINT  1024
#define NSAMPLE 32
#define C_FEAT  128
#define C_IN    131
#define C_OUT   256
#define R2      1e-2f   // float(0.1*0.1) as JAX weak-casts it

#define KT      5       // K tiles of 32 (131 -> 160 padded)
#define NT      16      // N tiles of 16 (256)
#define KPAD    168     // LDS row stride in bf16 elems

typedef __attribute__((ext_vector_type(8))) short bf16x8;
typedef __attribute__((ext_vector_type(4))) float f32x4;
typedef __attribute__((ext_vector_type(2))) float v2f;

__device__ __forceinline__ unsigned short f2bf(float f) {   // RNE, matches hw cvt
    unsigned u = __float_as_uint(f);
    return (unsigned short)((u + 0x7FFF + ((u >> 16) & 1)) >> 16);
}
__device__ __forceinline__ float bf2f(unsigned short h) {
    return __uint_as_float(((unsigned)h) << 16);
}

// forced VOP3P packed fp32 (full-rate on CDNA4; the compiler was scalarizing float2)
__device__ __forceinline__ v2f pk_add(v2f a, v2f b) {
    v2f d; asm("v_pk_add_f32 %0, %1, %2" : "=v"(d) : "v"(a), "v"(b)); return d;
}
__device__ __forceinline__ v2f pk_mul(v2f a, v2f b) {
    v2f d; asm("v_pk_mul_f32 %0, %1, %2" : "=v"(d) : "v"(a), "v"(b)); return d;
}

// ---------------- K0: split W into bf16 hi/lo, pre-swizzled into MFMA B-fragment order ----
__global__ __launch_bounds__(64) void k_wtrans(const float* __restrict__ W,
                                               unsigned short* __restrict__ Wb_hi,
                                               unsigned short* __restrict__ Wb_lo) {
    const int blk  = blockIdx.x;            // kt*NT + nt
    const int kt   = blk / NT, nt = blk % NT;
    const int lane = threadIdx.x;
    const int o    = nt * 16 + (lane & 15);
    const int k0   = kt * 32 + (lane >> 4) * 8;
    const size_t base = ((size_t)blk * 64 + lane) * 8;
#pragma unroll
    for (int j = 0; j < 8; ++j) {
        int k = k0 + j;
        float v = 0.0f;
        if (k < C_IN) {
            int src = (k < C_FEAT) ? (k + 3) : (k - C_FEAT);
            v = W[o * C_IN + src];
        }
        unsigned short hh = f2bf(v);
        Wb_hi[base + j] = hh;
        Wb_lo[base + j] = f2bf(v - bf2f(hh));
    }
}

// ---------------- K1: furthest point sampling (v4: forced-pk + branchless deferred argmax) ----
#define FPS_BLOCK 512
#define FPS_PPT   8     // 4 float2 pairs per thread

#define DPP_IMAX(x, ctrl, rmask)                                              \
    do {                                                                      \
        int _y = __builtin_amdgcn_update_dpp(x, x, ctrl, rmask, 0xf, false);  \
        x = (_y > x) ? _y : x;                                                \
    } while (0)

__global__ __launch_bounds__(FPS_BLOCK) void k_fps(const float* __restrict__ xyz,
                                                   float* __restrict__ new_xyz) {
    const int b    = blockIdx.x;
    const int t    = threadIdx.x;
    const int lane = t & 63;
    const int wid  = t >> 6;
    __shared__ float xl[N_PTS], yl[N_PTS], zl[N_PTS];
    __shared__ unsigned long long red[2][FPS_BLOCK / 64];

    const float* base = xyz + (size_t)b * N_PTS * 3;

    // negated pairs: nX[p] = {-x(2p), -x(2p+1)}  so dist uses pk_add(nX, {c,c}) = c - X
    v2f nX[4], nY[4], nZ[4], M[4];

    const float4* b4 = (const float4*)(base + (size_t)t * (FPS_PPT * 3));
    float4 v[6];
#pragma unroll
    for (int i = 0; i < 6; ++i) v[i] = b4[i];
    const float* vf = (const float*)v;
#pragma unroll
    for (int p = 0; p < 4; ++p) {
        float x0 = vf[(2 * p) * 3 + 0], x1 = vf[(2 * p + 1) * 3 + 0];
        float y0 = vf[(2 * p) * 3 + 1], y1 = vf[(2 * p + 1) * 3 + 1];
        float z0 = vf[(2 * p) * 3 + 2], z1 = vf[(2 * p + 1) * 3 + 2];
        nX[p] = (v2f){-x0, -x1};
        nY[p] = (v2f){-y0, -y1};
        nZ[p] = (v2f){-z0, -z1};
        M[p]  = (v2f){1e10f, 1e10f};
        int gi = t * FPS_PPT + 2 * p;
        xl[gi] = x0; xl[gi + 1] = x1;
        yl[gi] = y0; yl[gi + 1] = y1;
        zl[gi] = z0; zl[gi + 1] = z1;
    }
    __syncthreads();

    float cx = xl[0], cy = yl[0], cz = zl[0];
    if (t == 0) {
        float* o = new_xyz + (size_t)b * NPOINT * 3;
        o[0] = cx; o[1] = cy; o[2] = cz;
    }

    for (int it = 1; it < NPOINT; ++it) {
        const v2f ccx = (v2f){cx, cx};
        const v2f ccy = (v2f){cy, cy};
        const v2f ccz = (v2f){cz, cz};
        // ---- packed distance update: 8 pk ops + 2 scalar mins per pair ----
#pragma unroll
        for (int p = 0; p < 4; ++p) {
            v2f dx = pk_add(nX[p], ccx);            // c - x  (exact; square kills sign)
            v2f dy = pk_add(nY[p], ccy);
            v2f dz = pk_add(nZ[p], ccz);
            v2f xx = pk_mul(dx, dx);
            v2f yy = pk_mul(dy, dy);
            v2f zz = pk_mul(dz, dz);
            v2f d  = pk_add(pk_add(xx, yy), zz);    // ((dx2+dy2)+dz2) association
            M[p].x = fminf(M[p].x, d.x);
            M[p].y = fminf(M[p].y, d.y);
        }
        // ---- local max (value only) ----
        float a0 = fmaxf(M[0].x, M[0].y), a1 = fmaxf(M[1].x, M[1].y);
        float a2 = fmaxf(M[2].x, M[2].y), a3 = fmaxf(M[3].x, M[3].y);
        const float bestv = fmaxf(fmaxf(a0, a1), fmaxf(a2, a3));
        const int bb = __float_as_int(bestv);       // >=0: int order == float order
        // ---- wave DPP argmax ----
        int r = bb;
        DPP_IMAX(r, 0x111, 0xf);
        DPP_IMAX(r, 0x112, 0xf);
        DPP_IMAX(r, 0x114, 0xf);
        DPP_IMAX(r, 0x118, 0xf);
        DPP_IMAX(r, 0x142, 0xa);
        DPP_IMAX(r, 0x143, 0xc);
        const int vmax = __builtin_amdgcn_readlane(r, 63);
        const unsigned long long em = __ballot(bb == vmax);
        const int l = __ffsll((unsigned long long)em) - 1;  // lowest lane = lowest base idx
        // ---- branchless rescan on ALL lanes (overlaps ballot), descending keeps lowest j ----
        int selj = 0;
#pragma unroll
        for (int j = 7; j >= 0; --j) {
            int bits = __float_as_int((j & 1) ? M[j >> 1].y : M[j >> 1].x);
            selj = (bits == vmax) ? j : selj;
        }
        const int gidx = t * FPS_PPT + selj;
        const int widx = __builtin_amdgcn_readlane(gidx, l);
        if (lane == 0)
            red[it & 1][wid] = ((unsigned long long)(unsigned)vmax << 32)
                             | (unsigned)(N_PTS - 1 - widx);
        __syncthreads();
        // ---- cross-wave: 3-level tree over the 8 keys ----
        const unsigned long long* rp = red[it & 1];
        unsigned long long k0 = rp[0], k1 = rp[1], k2 = rp[2], k3 = rp[3];
        unsigned long long k4 = rp[4], k5 = rp[5], k6 = rp[6], k7 = rp[7];
        unsigned long long b01 = k0 > k1 ? k0 : k1;
        unsigned long long b23 = k2 > k3 ? k2 : k3;
        unsigned long long b45 = k4 > k5 ? k4 : k5;
        unsigned long long b67 = k6 > k7 ? k6 : k7;
        unsigned long long b03 = b01 > b23 ? b01 : b23;
        unsigned long long b47 = b45 > b67 ? b45 : b67;
        unsigned long long best = b03 > b47 ? b03 : b47;
        const int idx = N_PTS - 1 - (int)(best & 0xFFFFull);
        cx = xl[idx]; cy = yl[idx]; cz = zl[idx];
        if (t == 0) {
            float* o = new_xyz + ((size_t)b * NPOINT + it) * 3;
            o[0] = cx; o[1] = cy; o[2] = cz;
        }
    }
}

// ---------------- K2: ball query (unchanged) ----------------
__global__ __launch_bounds__(256) void k_ballquery(const float* __restrict__ xyz,
                                                   const float* __restrict__ new_xyz,
                                                   int* __restrict__ out_idx) {
    const int lane = threadIdx.x & 63;
    const int wid  = threadIdx.x >> 6;
    const int b    = blockIdx.y;
    const int s    = blockIdx.x * 4 + wid;

    const float* xb = xyz + (size_t)b * N_PTS * 3;
    const float* q  = new_xyz + ((size_t)b * NPOINT + s) * 3;
    float qx = q[0], qy = q[1], qz = q[2];
    int* ob = out_idx + ((size_t)b * NPOINT + s) * NSAMPLE;

    int total = 0, first = -1;
    const unsigned long long mlt = (1ull << lane) - 1ull;

    for (int ch = 0; ch < N_PTS / 64; ++ch) {
        int i = ch * 64 + lane;
        float x = xb[i * 3 + 0], y = xb[i * 3 + 1], z = xb[i * 3 + 2];
        float dx = qx - x, dy = qy - y, dz = qz - z;
        float d2 = ((dx * dx) + (dy * dy)) + (dz * dz);
        bool valid = d2 < R2;
        unsigned long long m = __ballot(valid);
        if (valid) {
            int pos = total + __popcll(m & mlt);
            if (pos < NSAMPLE) ob[pos] = i;
        }
        if (first < 0 && m != 0ull) first = ch * 64 + (__ffsll(m) - 1);
        total += __popcll(m);
        if (total >= NSAMPLE) break;
    }
    if (total < NSAMPLE) {
        if (lane >= total && lane < NSAMPLE) ob[lane] = first;
    }
}

// ---------------- K3: gather + BN + ReLU + split-bf16 MFMA GEMM + max ----------------
__device__ __forceinline__ float bn_relu(float v, float mean, float scale, float beta) {
    float r = ((v - mean) * scale) + beta;
    return fmaxf(r, 0.0f);
}

__global__ __launch_bounds__(256) void k_group_gemm(
    const float* __restrict__ xyz, const float* __restrict__ feat,
    const float* __restrict__ new_xyz, const int* __restrict__ idx,
    const unsigned short* __restrict__ Wb_hi, const unsigned short* __restrict__ Wb_lo,
    const float* __restrict__ bias,
    const float* __restrict__ bn_g, const float* __restrict__ bn_b,
    const float* __restrict__ bn_m, const float* __restrict__ bn_v,
    float* __restrict__ out) {
    const int sx = blockIdx.x;
    const int s  = ((sx & 7) << 7) | (sx >> 3);   // 128-long contiguous s-runs per XCD
    const int b  = blockIdx.y;
    const int t  = threadIdx.x;
    const int lane = t & 63;
    const int w    = t >> 6;

    __shared__ unsigned short Xh[32][KPAD], Xl[32][KPAD];
    __shared__ float sc_l[C_IN], mn_l[C_IN], bt_l[C_IN];
    __shared__ int   idxs[NSAMPLE];
    __shared__ float nq[3];

    if (t < C_IN) {
        float g  = bn_g[t];
        float vv = bn_v[t] + 1e-5f;
        sc_l[t] = g / sqrtf(vv);
        mn_l[t] = bn_m[t];
        bt_l[t] = bn_b[t];
    }
    if (t < NSAMPLE) idxs[t] = idx[((size_t)b * NPOINT + s) * NSAMPLE + t];
    if (t < 3)       nq[t]   = new_xyz[((size_t)b * NPOINT + s) * 3 + t];
    __syncthreads();

    {
        const int ks = t & 31;
        const int qh = t >> 5;
        const float* frow = feat + ((size_t)b * N_PTS + idxs[ks]) * C_FEAT;
#pragma unroll
        for (int m = 0; m < 4; ++m) {
            int qq = m * 8 + qh;
            int c0 = qq * 4;
            float4 f = *(const float4*)&frow[c0];
            float v0 = bn_relu(f.x, mn_l[3 + c0 + 0], sc_l[3 + c0 + 0], bt_l[3 + c0 + 0]);
            float v1 = bn_relu(f.y, mn_l[3 + c0 + 1], sc_l[3 + c0 + 1], bt_l[3 + c0 + 1]);
            float v2 = bn_relu(f.z, mn_l[3 + c0 + 2], sc_l[3 + c0 + 2], bt_l[3 + c0 + 2]);
            float v3 = bn_relu(f.w, mn_l[3 + c0 + 3], sc_l[3 + c0 + 3], bt_l[3 + c0 + 3]);
            unsigned short h0 = f2bf(v0), h1 = f2bf(v1), h2 = f2bf(v2), h3 = f2bf(v3);
            uint2 hv, lv;
            hv.x = (unsigned)h0 | ((unsigned)h1 << 16);
            hv.y = (unsigned)h2 | ((unsigned)h3 << 16);
            lv.x = (unsigned)f2bf(v0 - bf2f(h0)) | ((unsigned)f2bf(v1 - bf2f(h1)) << 16);
            lv.y = (unsigned)f2bf(v2 - bf2f(h2)) | ((unsigned)f2bf(v3 - bf2f(h3)) << 16);
            *(uint2*)&Xh[ks][c0] = hv;
            *(uint2*)&Xl[ks][c0] = lv;
        }
    }
    if (t < 32) {
        const int row = t;
        const int id  = idxs[row];
        const float* p = xyz + ((size_t)b * N_PTS + id) * 3;
        uint4 z4 = {0u, 0u, 0u, 0u};
        uint4 hh = z4, ll = z4;
        unsigned short h[3];
#pragma unroll
        for (int d = 0; d < 3; ++d) {
            float g = p[d] - nq[d];
            float v = bn_relu(g, mn_l[d], sc_l[d], bt_l[d]);
            h[d] = f2bf(v);
            unsigned short lo = f2bf(v - bf2f(h[d]));
            if (d == 0) { hh.x |= h[d];                 ll.x |= lo; }
            if (d == 1) { hh.x |= (unsigned)h[d] << 16; ll.x |= (unsigned)lo << 16; }
            if (d == 2) { hh.y |= h[d];                 ll.y |= lo; }
        }
        *(uint4*)&Xh[row][128] = hh;  *(uint4*)&Xl[row][128] = ll;
        *(uint4*)&Xh[row][136] = z4;  *(uint4*)&Xl[row][136] = z4;
        *(uint4*)&Xh[row][144] = z4;  *(uint4*)&Xl[row][144] = z4;
        *(uint4*)&Xh[row][152] = z4;  *(uint4*)&Xl[row][152] = z4;
        *(uint4*)&Xh[row][160] = z4;  *(uint4*)&Xl[row][160] = z4;
    }
    __syncthreads();

    f32x4 zero = {0.f, 0.f, 0.f, 0.f};
    f32x4 acc[2][4];
#pragma unroll
    for (int m = 0; m < 2; ++m)
#pragma unroll
        for (int n = 0; n < 4; ++n) acc[m][n] = zero;

    const int r0 = lane & 15;
#pragma unroll
    for (int kt = 0; kt < KT; ++kt) {
        const int k0 = kt * 32 + (lane >> 4) * 8;
        bf16x8 a0h = *(const bf16x8*)&Xh[r0][k0];
        bf16x8 a1h = *(const bf16x8*)&Xh[16 + r0][k0];
        bf16x8 a0l = *(const bf16x8*)&Xl[r0][k0];
        bf16x8 a1l = *(const bf16x8*)&Xl[16 + r0][k0];
#pragma unroll
        for (int n = 0; n < 4; ++n) {
            const int nt = w * 4 + n;
            const size_t off = (((size_t)kt * NT + nt) * 64 + lane) * 8;
            bf16x8 bh = *(const bf16x8*)&Wb_hi[off];
            bf16x8 bl = *(const bf16x8*)&Wb_lo[off];
            acc[0][n] = __builtin_amdgcn_mfma_f32_16x16x32_bf16(a0h, bh, acc[0][n], 0, 0, 0);
            acc[1][n] = __builtin_amdgcn_mfma_f32_16x16x32_bf16(a1h, bh, acc[1][n], 0, 0, 0);
            acc[0][n] = __builtin_amdgcn_mfma_f32_16x16x32_bf16(a0l, bh, acc[0][n], 0, 0, 0);
            acc[1][n] = __builtin_amdgcn_mfma_f32_16x16x32_bf16(a1l, bh, acc[1][n], 0, 0, 0);
            acc[0][n] = __builtin_amdgcn_mfma_f32_16x16x32_bf16(a0h, bl, acc[0][n], 0, 0, 0);
            acc[1][n] = __builtin_amdgcn_mfma_f32_16x16x32_bf16(a1h, bl, acc[1][n], 0, 0, 0);
        }
    }

#pragma unroll
    for (int n = 0; n < 4; ++n) {
        float m0 = fmaxf(acc[0][n][0], acc[1][n][0]);
        float m1 = fmaxf(acc[0][n][1], acc[1][n][1]);
        float m2 = fmaxf(acc[0][n][2], acc[1][n][2]);
        float m3 = fmaxf(acc[0][n][3], acc[1][n][3]);
        float pm = fmaxf(fmaxf(m0, m1), fmaxf(m2, m3));
        pm = fmaxf(pm, __shfl_xor(pm, 16));
        pm = fmaxf(pm, __shfl_xor(pm, 32));
        if (lane < 16) {
            int o = (w * 4 + n) * 16 + lane;
            out[(size_t)b * C_OUT * NPOINT + (size_t)o * NPOINT + s] = pm + bias[o];
        }
    }
}

extern "C" void kernel_launch(void* const* d_in, const int* in_sizes, int n_in,
                              void* d_out, int out_size, void* d_ws, size_t ws_size,
                              hipStream_t stream) {
    const float* xyz  = (const float*)d_in[0];
    const float* feat = (const float*)d_in[1];
    const float* W    = (const float*)d_in[2];
    const float* bias = (const float*)d_in[3];
    const float* bn_g = (const float*)d_in[4];
    const float* bn_b = (const float*)d_in[5];
    const float* bn_m = (const float*)d_in[6];
    const float* bn_v = (const float*)d_in[7];

    float* new_xyz  = (float*)d_out;                                   // (8,1024,3)
    float* out_feat = (float*)d_out + (size_t)B_SZ * NPOINT * 3;       // (8,256,1024)

    int*            ws_idx = (int*)d_ws;
    unsigned short* Wb_hi  = (unsigned short*)((char*)d_ws + (size_t)B_SZ * NPOINT * NSAMPLE * sizeof(int));
    unsigned short* Wb_lo  = Wb_hi + (size_t)KT * NT * 64 * 8;

    hipLaunchKernelGGL(k_wtrans, dim3(KT * NT), dim3(64), 0, stream, W, Wb_hi, Wb_lo);
    hipLaunchKernelGGL(k_fps, dim3(B_SZ), dim3(FPS_BLOCK), 0, stream, xyz, new_xyz);
    hipLaunchKernelGGL(k_ballquery, dim3(NPOINT / 4, B_SZ), dim3(256), 0, stream,
                       xyz, new_xyz, ws_idx);
    hipLaunchKernelGGL(k_group_gemm, dim3(NPOINT, B_SZ), dim3(256), 0, stream,
                       xyz, feat, new_xyz, ws_idx, Wb_hi, Wb_lo, bias,
                       bn_g, bn_b, bn_m, bn_v, out_feat);
}

// Round 7
// 807.046 us; speedup vs baseline: 1.1129x; 1.0834x over previous
//
#pragma clang fp contract(off)
#include <hip/hip_runtime.h>
#include <math.h>

#define N_PTS   4096
#define B_SZ    8
#define NPOINT  1024
#define NSAMPLE 32
#define C_FEAT  128
#define C_IN    131
#define C_OUT   256
#define R2      1e-2f   // float(0.1*0.1) as JAX weak-casts it

#define KT      5       // K tiles of 32 (131 -> 160 padded)
#define NT      16      // N tiles of 16 (256)
#define KPAD    168     // LDS row stride in bf16 elems

typedef __attribute__((ext_vector_type(8))) short bf16x8;
typedef __attribute__((ext_vector_type(4))) float f32x4;
typedef __attribute__((ext_vector_type(2))) float v2f;

__device__ __forceinline__ unsigned short f2bf(float f) {   // RNE, matches hw cvt
    unsigned u = __float_as_uint(f);
    return (unsigned short)((u + 0x7FFF + ((u >> 16) & 1)) >> 16);
}
__device__ __forceinline__ float bf2f(unsigned short h) {
    return __uint_as_float(((unsigned)h) << 16);
}

// forced VOP3P packed fp32 (full-rate on CDNA4)
__device__ __forceinline__ v2f pk_add(v2f a, v2f b) {
    v2f d; asm("v_pk_add_f32 %0, %1, %2" : "=v"(d) : "v"(a), "v"(b)); return d;
}
__device__ __forceinline__ v2f pk_mul(v2f a, v2f b) {
    v2f d; asm("v_pk_mul_f32 %0, %1, %2" : "=v"(d) : "v"(a), "v"(b)); return d;
}

// ---------------- K0: split W into bf16 hi/lo, pre-swizzled into MFMA B-fragment order ----
__global__ __launch_bounds__(64) void k_wtrans(const float* __restrict__ W,
                                               unsigned short* __restrict__ Wb_hi,
                                               unsigned short* __restrict__ Wb_lo) {
    const int blk  = blockIdx.x;            // kt*NT + nt
    const int kt   = blk / NT, nt = blk % NT;
    const int lane = threadIdx.x;
    const int o    = nt * 16 + (lane & 15);
    const int k0   = kt * 32 + (lane >> 4) * 8;
    const size_t base = ((size_t)blk * 64 + lane) * 8;
#pragma unroll
    for (int j = 0; j < 8; ++j) {
        int k = k0 + j;
        float v = 0.0f;
        if (k < C_IN) {
            int src = (k < C_FEAT) ? (k + 3) : (k - C_FEAT);
            v = W[o * C_IN + src];
        }
        unsigned short hh = f2bf(v);
        Wb_hi[base + j] = hh;
        Wb_lo[base + j] = f2bf(v - bf2f(hh));
    }
}

// ---------------- K1: furthest point sampling (v5: 4 waves, index-carrying DPP argmax) ----
#define FPS_BLOCK 256
#define FPS_PPT   16    // 8 float2 pairs per thread
#define FPS_NW    (FPS_BLOCK / 64)

// argmax-carrying DPP step: incoming (_nb,_ni) is from a LOWER lane for
// row_shr / row_bcast patterns; >= keeps the lower lane (= lower index) on ties.
#define DPP_ARGMAX(vb, vi, ctrl, rmask)                                           \
    do {                                                                          \
        int _nb = __builtin_amdgcn_update_dpp(vb, vb, ctrl, rmask, 0xf, false);   \
        int _ni = __builtin_amdgcn_update_dpp(vi, vi, ctrl, rmask, 0xf, false);   \
        bool _g = (_nb >= vb);                                                    \
        vb = _g ? _nb : vb;                                                       \
        vi = _g ? _ni : vi;                                                       \
    } while (0)

// in-lane combine: b-side is the strictly-higher index block; strict > keeps lowest idx
#define CMB(ab, aj, bb_, bj_)                                                     \
    do {                                                                          \
        bool _g = ((bb_) > (ab));                                                 \
        ab = _g ? (bb_) : (ab);                                                   \
        aj = _g ? (bj_) : (aj);                                                   \
    } while (0)

__global__ __launch_bounds__(FPS_BLOCK) void k_fps(const float* __restrict__ xyz,
                                                   float* __restrict__ new_xyz) {
    const int b    = blockIdx.x;
    const int t    = threadIdx.x;
    const int lane = t & 63;
    const int wid  = t >> 6;
    __shared__ float4 xyzw[N_PTS];                     // 64 KB, read-only after init
    __shared__ unsigned long long red[2][FPS_NW];

    const float* base = xyz + (size_t)b * N_PTS * 3;

    // negated pairs: nX[p] = {-x(2p), -x(2p+1)} so dist = pk_add(nX, {c,c}) = c - X (exact)
    v2f nX[8], nY[8], nZ[8], M[8];

    const float4* b4 = (const float4*)(base + (size_t)t * (FPS_PPT * 3));
    float4 v[12];
#pragma unroll
    for (int i = 0; i < 12; ++i) v[i] = b4[i];
    const float* vf = (const float*)v;
#pragma unroll
    for (int p = 0; p < 8; ++p) {
        float x0 = vf[(2 * p) * 3 + 0], x1 = vf[(2 * p + 1) * 3 + 0];
        float y0 = vf[(2 * p) * 3 + 1], y1 = vf[(2 * p + 1) * 3 + 1];
        float z0 = vf[(2 * p) * 3 + 2], z1 = vf[(2 * p + 1) * 3 + 2];
        nX[p] = (v2f){-x0, -x1};
        nY[p] = (v2f){-y0, -y1};
        nZ[p] = (v2f){-z0, -z1};
        M[p]  = (v2f){1e10f, 1e10f};
        int gi = t * FPS_PPT + 2 * p;
        xyzw[gi]     = (float4){x0, y0, z0, 0.0f};
        xyzw[gi + 1] = (float4){x1, y1, z1, 0.0f};
    }
    __syncthreads();

    float4 c4 = xyzw[0];                               // broadcast read
    float cx = c4.x, cy = c4.y, cz = c4.z;
    if (t == 0) {
        float* o = new_xyz + (size_t)b * NPOINT * 3;
        o[0] = cx; o[1] = cy; o[2] = cz;
    }

    for (int it = 1; it < NPOINT; ++it) {
        const v2f ccx = (v2f){cx, cx};
        const v2f ccy = (v2f){cy, cy};
        const v2f ccz = (v2f){cz, cz};
        int pb[8], pj[8];                              // per-pair winner (bits, j)
#pragma unroll
        for (int p = 0; p < 8; ++p) {
            v2f dx = pk_add(nX[p], ccx);
            v2f dy = pk_add(nY[p], ccy);
            v2f dz = pk_add(nZ[p], ccz);
            v2f xx = pk_mul(dx, dx);
            v2f yy = pk_mul(dy, dy);
            v2f zz = pk_mul(dz, dz);
            v2f d  = pk_add(pk_add(xx, yy), zz);       // ((dx2+dy2)+dz2)
            M[p].x = fminf(M[p].x, d.x);
            M[p].y = fminf(M[p].y, d.y);
            int bx = __float_as_int(M[p].x);           // >=0: int order == float order
            int by = __float_as_int(M[p].y);
            bool g = by > bx;                          // strict: tie keeps even (lower) j
            pb[p] = g ? by : bx;
            pj[p] = g ? (2 * p + 1) : (2 * p);
        }
        // in-lane tree 8 pairs -> 1 (b-side always higher index block)
        CMB(pb[0], pj[0], pb[1], pj[1]);
        CMB(pb[2], pj[2], pb[3], pj[3]);
        CMB(pb[4], pj[4], pb[5], pj[5]);
        CMB(pb[6], pj[6], pb[7], pj[7]);
        CMB(pb[0], pj[0], pb[2], pj[2]);
        CMB(pb[4], pj[4], pb[6], pj[6]);
        CMB(pb[0], pj[0], pb[4], pj[4]);
        int vb = pb[0];
        int vi = t * FPS_PPT + pj[0];                  // global index
        // wave argmax carrying the index (6 DPP steps, ties -> lower lane)
        DPP_ARGMAX(vb, vi, 0x111, 0xf);                // row_shr:1
        DPP_ARGMAX(vb, vi, 0x112, 0xf);                // row_shr:2
        DPP_ARGMAX(vb, vi, 0x114, 0xf);                // row_shr:4
        DPP_ARGMAX(vb, vi, 0x118, 0xf);                // row_shr:8
        DPP_ARGMAX(vb, vi, 0x142, 0xa);                // row_bcast:15
        DPP_ARGMAX(vb, vi, 0x143, 0xc);                // row_bcast:31
        if (lane == 63)
            red[it & 1][wid] = ((unsigned long long)(unsigned)vb << 32)
                             | (unsigned)(N_PTS - 1 - vi);
        __syncthreads();
        // cross-wave: tree over 4 u64 keys (unique idx -> no ties possible)
        const unsigned long long* rp = red[it & 1];
        unsigned long long k0 = rp[0], k1 = rp[1], k2 = rp[2], k3 = rp[3];
        unsigned long long b01 = k0 > k1 ? k0 : k1;
        unsigned long long b23 = k2 > k3 ? k2 : k3;
        unsigned long long best = b01 > b23 ? b01 : b23;
        const int idx = N_PTS - 1 - (int)(best & 0xFFFFull);
        float4 w4 = xyzw[idx];                         // single ds_read_b128 broadcast
        cx = w4.x; cy = w4.y; cz = w4.z;
        if (t == 0) {
            float* o = new_xyz + ((size_t)b * NPOINT + it) * 3;
            o[0] = cx; o[1] = cy; o[2] = cz;
        }
    }
}

// ---------------- K2: ball query (unchanged) ----------------
__global__ __launch_bounds__(256) void k_ballquery(const float* __restrict__ xyz,
                                                   const float* __restrict__ new_xyz,
                                                   int* __restrict__ out_idx) {
    const int lane = threadIdx.x & 63;
    const int wid  = threadIdx.x >> 6;
    const int b    = blockIdx.y;
    const int s    = blockIdx.x * 4 + wid;

    const float* xb = xyz + (size_t)b * N_PTS * 3;
    const float* q  = new_xyz + ((size_t)b * NPOINT + s) * 3;
    float qx = q[0], qy = q[1], qz = q[2];
    int* ob = out_idx + ((size_t)b * NPOINT + s) * NSAMPLE;

    int total = 0, first = -1;
    const unsigned long long mlt = (1ull << lane) - 1ull;

    for (int ch = 0; ch < N_PTS / 64; ++ch) {
        int i = ch * 64 + lane;
        float x = xb[i * 3 + 0], y = xb[i * 3 + 1], z = xb[i * 3 + 2];
        float dx = qx - x, dy = qy - y, dz = qz - z;
        float d2 = ((dx * dx) + (dy * dy)) + (dz * dz);
        bool valid = d2 < R2;
        unsigned long long m = __ballot(valid);
        if (valid) {
            int pos = total + __popcll(m & mlt);
            if (pos < NSAMPLE) ob[pos] = i;
        }
        if (first < 0 && m != 0ull) first = ch * 64 + (__ffsll(m) - 1);
        total += __popcll(m);
        if (total >= NSAMPLE) break;
    }
    if (total < NSAMPLE) {
        if (lane >= total && lane < NSAMPLE) ob[lane] = first;
    }
}

// ---------------- K3: gather + BN + ReLU + split-bf16 MFMA GEMM + max ----------------
__device__ __forceinline__ float bn_relu(float v, float mean, float scale, float beta) {
    float r = ((v - mean) * scale) + beta;
    return fmaxf(r, 0.0f);
}

__global__ __launch_bounds__(256) void k_group_gemm(
    const float* __restrict__ xyz, const float* __restrict__ feat,
    const float* __restrict__ new_xyz, const int* __restrict__ idx,
    const unsigned short* __restrict__ Wb_hi, const unsigned short* __restrict__ Wb_lo,
    const float* __restrict__ bias,
    const float* __restrict__ bn_g, const float* __restrict__ bn_b,
    const float* __restrict__ bn_m, const float* __restrict__ bn_v,
    float* __restrict__ out) {
    const int sx = blockIdx.x;
    const int s  = ((sx & 7) << 7) | (sx >> 3);   // 128-long contiguous s-runs per XCD
    const int b  = blockIdx.y;
    const int t  = threadIdx.x;
    const int lane = t & 63;
    const int w    = t >> 6;

    __shared__ unsigned short Xh[32][KPAD], Xl[32][KPAD];
    __shared__ float sc_l[C_IN], mn_l[C_IN], bt_l[C_IN];
    __shared__ int   idxs[NSAMPLE];
    __shared__ float nq[3];

    if (t < C_IN) {
        float g  = bn_g[t];
        float vv = bn_v[t] + 1e-5f;
        sc_l[t] = g / sqrtf(vv);
        mn_l[t] = bn_m[t];
        bt_l[t] = bn_b[t];
    }
    if (t < NSAMPLE) idxs[t] = idx[((size_t)b * NPOINT + s) * NSAMPLE + t];
    if (t < 3)       nq[t]   = new_xyz[((size_t)b * NPOINT + s) * 3 + t];
    __syncthreads();

    {
        const int ks = t & 31;
        const int qh = t >> 5;
        const float* frow = feat + ((size_t)b * N_PTS + idxs[ks]) * C_FEAT;
#pragma unroll
        for (int m = 0; m < 4; ++m) {
            int qq = m * 8 + qh;
            int c0 = qq * 4;
            float4 f = *(const float4*)&frow[c0];
            float v0 = bn_relu(f.x, mn_l[3 + c0 + 0], sc_l[3 + c0 + 0], bt_l[3 + c0 + 0]);
            float v1 = bn_relu(f.y, mn_l[3 + c0 + 1], sc_l[3 + c0 + 1], bt_l[3 + c0 + 1]);
            float v2 = bn_relu(f.z, mn_l[3 + c0 + 2], sc_l[3 + c0 + 2], bt_l[3 + c0 + 2]);
            float v3 = bn_relu(f.w, mn_l[3 + c0 + 3], sc_l[3 + c0 + 3], bt_l[3 + c0 + 3]);
            unsigned short h0 = f2bf(v0), h1 = f2bf(v1), h2 = f2bf(v2), h3 = f2bf(v3);
            uint2 hv, lv;
            hv.x = (unsigned)h0 | ((unsigned)h1 << 16);
            hv.y = (unsigned)h2 | ((unsigned)h3 << 16);
            lv.x = (unsigned)f2bf(v0 - bf2f(h0)) | ((unsigned)f2bf(v1 - bf2f(h1)) << 16);
            lv.y = (unsigned)f2bf(v2 - bf2f(h2)) | ((unsigned)f2bf(v3 - bf2f(h3)) << 16);
            *(uint2*)&Xh[ks][c0] = hv;
            *(uint2*)&Xl[ks][c0] = lv;
        }
    }
    if (t < 32) {
        const int row = t;
        const int id  = idxs[row];
        const float* p = xyz + ((size_t)b * N_PTS + id) * 3;
        uint4 z4 = {0u, 0u, 0u, 0u};
        uint4 hh = z4, ll = z4;
        unsigned short h[3];
#pragma unroll
        for (int d = 0; d < 3; ++d) {
            float g = p[d] - nq[d];
            float v = bn_relu(g, mn_l[d], sc_l[d], bt_l[d]);
            h[d] = f2bf(v);
            unsigned short lo = f2bf(v - bf2f(h[d]));
            if (d == 0) { hh.x |= h[d];                 ll.x |= lo; }
            if (d == 1) { hh.x |= (unsigned)h[d] << 16; ll.x |= (unsigned)lo << 16; }
            if (d == 2) { hh.y |= h[d];                 ll.y |= lo; }
        }
        *(uint4*)&Xh[row][128] = hh;  *(uint4*)&Xl[row][128] = ll;
        *(uint4*)&Xh[row][136] = z4;  *(uint4*)&Xl[row][136] = z4;
        *(uint4*)&Xh[row][144] = z4;  *(uint4*)&Xl[row][144] = z4;
        *(uint4*)&Xh[row][152] = z4;  *(uint4*)&Xl[row][152] = z4;
        *(uint4*)&Xh[row][160] = z4;  *(uint4*)&Xl[row][160] = z4;
    }
    __syncthreads();

    f32x4 zero = {0.f, 0.f, 0.f, 0.f};
    f32x4 acc[2][4];
#pragma unroll
    for (int m = 0; m < 2; ++m)
#pragma unroll
        for (int n = 0; n < 4; ++n) acc[m][n] = zero;

    const int r0 = lane & 15;
#pragma unroll
    for (int kt = 0; kt < KT; ++kt) {
        const int k0 = kt * 32 + (lane >> 4) * 8;
        bf16x8 a0h = *(const bf16x8*)&Xh[r0][k0];
        bf16x8 a1h = *(const bf16x8*)&Xh[16 + r0][k0];
        bf16x8 a0l = *(const bf16x8*)&Xl[r0][k0];
        bf16x8 a1l = *(const bf16x8*)&Xl[16 + r0][k0];
#pragma unroll
        for (int n = 0; n < 4; ++n) {
            const int nt = w * 4 + n;
            const size_t off = (((size_t)kt * NT + nt) * 64 + lane) * 8;
            bf16x8 bh = *(const bf16x8*)&Wb_hi[off];
            bf16x8 bl = *(const bf16x8*)&Wb_lo[off];
            acc[0][n] = __builtin_amdgcn_mfma_f32_16x16x32_bf16(a0h, bh, acc[0][n], 0, 0, 0);
            acc[1][n] = __builtin_amdgcn_mfma_f32_16x16x32_bf16(a1h, bh, acc[1][n], 0, 0, 0);
            acc[0][n] = __builtin_amdgcn_mfma_f32_16x16x32_bf16(a0l, bh, acc[0][n], 0, 0, 0);
            acc[1][n] = __builtin_amdgcn_mfma_f32_16x16x32_bf16(a1l, bh, acc[1][n], 0, 0, 0);
            acc[0][n] = __builtin_amdgcn_mfma_f32_16x16x32_bf16(a0h, bl, acc[0][n], 0, 0, 0);
            acc[1][n] = __builtin_amdgcn_mfma_f32_16x16x32_bf16(a1h, bl, acc[1][n], 0, 0, 0);
        }
    }

#pragma unroll
    for (int n = 0; n < 4; ++n) {
        float m0 = fmaxf(acc[0][n][0], acc[1][n][0]);
        float m1 = fmaxf(acc[0][n][1], acc[1][n][1]);
        float m2 = fmaxf(acc[0][n][2], acc[1][n][2]);
        float m3 = fmaxf(acc[0][n][3], acc[1][n][3]);
        float pm = fmaxf(fmaxf(m0, m1), fmaxf(m2, m3));
        pm = fmaxf(pm, __shfl_xor(pm, 16));
        pm = fmaxf(pm, __shfl_xor(pm, 32));
        if (lane < 16) {
            int o = (w * 4 + n) * 16 + lane;
            out[(size_t)b * C_OUT * NPOINT + (size_t)o * NPOINT + s] = pm + bias[o];
        }
    }
}

extern "C" void kernel_launch(void* const* d_in, const int* in_sizes, int n_in,
                              void* d_out, int out_size, void* d_ws, size_t ws_size,
                              hipStream_t stream) {
    const float* xyz  = (const float*)d_in[0];
    const float* feat = (const float*)d_in[1];
    const float* W    = (const float*)d_in[2];
    const float* bias = (const float*)d_in[3];
    const float* bn_g = (const float*)d_in[4];
    const float* bn_b = (const float*)d_in[5];
    const float* bn_m = (const float*)d_in[6];
    const float* bn_v = (const float*)d_in[7];

    float* new_xyz  = (float*)d_out;                                   // (8,1024,3)
    float* out_feat = (float*)d_out + (size_t)B_SZ * NPOINT * 3;       // (8,256,1024)

    int*            ws_idx = (int*)d_ws;
    unsigned short* Wb_hi  = (unsigned short*)((char*)d_ws + (size_t)B_SZ * NPOINT * NSAMPLE * sizeof(int));
    unsigned short* Wb_lo  = Wb_hi + (size_t)KT * NT * 64 * 8;

    hipLaunchKernelGGL(k_wtrans, dim3(KT * NT), dim3(64), 0, stream, W, Wb_hi, Wb_lo);
    hipLaunchKernelGGL(k_fps, dim3(B_SZ), dim3(FPS_BLOCK), 0, stream, xyz, new_xyz);
    hipLaunchKernelGGL(k_ballquery, dim3(NPOINT / 4, B_SZ), dim3(256), 0, stream,
                       xyz, new_xyz, ws_idx);
    hipLaunchKernelGGL(k_group_gemm, dim3(NPOINT, B_SZ), dim3(256), 0, stream,
                       xyz, feat, new_xyz, ws_idx, Wb_hi, Wb_lo, bias,
                       bn_g, bn_b, bn_m, bn_v, out_feat);
}

// Round 8
// 772.412 us; speedup vs baseline: 1.1628x; 1.0448x over previous
//
#pragma clang fp contract(off)
#include <hip/hip_runtime.h>
#include <math.h>

#define N_PTS   4096
#define B_SZ    8
#define NPOINT  1024
#define NSAMPLE 32
#define C_FEAT  128
#define C_IN    131
#define C_OUT   256
#define R2      1e-2f   // float(0.1*0.1) as JAX weak-casts it

#define KT      5       // K tiles of 32 (131 -> 160 padded)
#define NT      16      // N tiles of 16 (256)
#define KPAD    168     // LDS row stride in bf16 elems
#define NITEMS  (B_SZ * NPOINT)   // one item = one (b, s)

typedef __attribute__((ext_vector_type(8))) short bf16x8;
typedef __attribute__((ext_vector_type(4))) float f32x4;
typedef __attribute__((ext_vector_type(2))) float v2f;

__device__ __forceinline__ unsigned short f2bf(float f) {   // RNE, matches hw cvt
    unsigned u = __float_as_uint(f);
    return (unsigned short)((u + 0x7FFF + ((u >> 16) & 1)) >> 16);
}
__device__ __forceinline__ float bf2f(unsigned short h) {
    return __uint_as_float(((unsigned)h) << 16);
}

// forced VOP3P packed fp32 (full-rate on CDNA4)
__device__ __forceinline__ v2f pk_add(v2f a, v2f b) {
    v2f d; asm("v_pk_add_f32 %0, %1, %2" : "=v"(d) : "v"(a), "v"(b)); return d;
}
__device__ __forceinline__ v2f pk_mul(v2f a, v2f b) {
    v2f d; asm("v_pk_mul_f32 %0, %1, %2" : "=v"(d) : "v"(a), "v"(b)); return d;
}

// ---------------- K-zero: reset flags + work cursor (ws re-poisoned every replay) ----
__global__ void k_zero(unsigned* __restrict__ ctrl) {
    if (threadIdx.x < 16) ctrl[threadIdx.x] = 0u;
}

// ---------------- K0: split W into bf16 hi/lo, pre-swizzled into MFMA B-fragment order ----
__global__ __launch_bounds__(64) void k_wtrans(const float* __restrict__ W,
                                               unsigned short* __restrict__ Wb_hi,
                                               unsigned short* __restrict__ Wb_lo) {
    const int blk  = blockIdx.x;            // kt*NT + nt
    const int kt   = blk / NT, nt = blk % NT;
    const int lane = threadIdx.x;
    const int o    = nt * 16 + (lane & 15);
    const int k0   = kt * 32 + (lane >> 4) * 8;
    const size_t base = ((size_t)blk * 64 + lane) * 8;
#pragma unroll
    for (int j = 0; j < 8; ++j) {
        int k = k0 + j;
        float v = 0.0f;
        if (k < C_IN) {
            int src = (k < C_FEAT) ? (k + 3) : (k - C_FEAT);
            v = W[o * C_IN + src];
        }
        unsigned short hh = f2bf(v);
        Wb_hi[base + j] = hh;
        Wb_lo[base + j] = f2bf(v - bf2f(hh));
    }
}

// ---------------- FPS helpers (R7-proven) ----------------
#define FPS_BLOCK 256
#define FPS_PPT   16    // 8 float2 pairs per thread
#define FPS_NW    (FPS_BLOCK / 64)

#define DPP_ARGMAX(vb, vi, ctrl_, rmask)                                          \
    do {                                                                          \
        int _nb = __builtin_amdgcn_update_dpp(vb, vb, ctrl_, rmask, 0xf, false);  \
        int _ni = __builtin_amdgcn_update_dpp(vi, vi, ctrl_, rmask, 0xf, false);  \
        bool _g = (_nb >= vb);                                                    \
        vb = _g ? _nb : vb;                                                       \
        vi = _g ? _ni : vi;                                                       \
    } while (0)

#define CMB(ab, aj, bb_, bj_)                                                     \
    do {                                                                          \
        bool _g = ((bb_) > (ab));                                                 \
        ab = _g ? (bb_) : (ab);                                                   \
        aj = _g ? (bj_) : (aj);                                                   \
    } while (0)

__device__ __forceinline__ float bn_relu(float v, float mean, float scale, float beta) {
    float r = ((v - mean) * scale) + beta;
    return fmaxf(r, 0.0f);
}

// ---------------- MEGA kernel: fps (blocks 0-7) + pipelined bq+gemm workers ----------------
// smem layout (union by role):
//   fps:    xyzw float4[4096] @0 (65536), red u64[2][4] @65536
//   worker: Xh @0 (10752), Xl @10752, sc @21504, mn @22032, bt @22560,
//           idxs @23088 (32 int), nq @23216 (3 f), item @23232 (int)
// 84000 B total -> 1 block/CU guaranteed (no worker co-resident with an fps block).
__global__ __launch_bounds__(256) void k_mega(
    const float* __restrict__ xyz, const float* __restrict__ feat,
    const unsigned short* __restrict__ Wb_hi, const unsigned short* __restrict__ Wb_lo,
    const float* __restrict__ bias,
    const float* __restrict__ bn_g, const float* __restrict__ bn_b,
    const float* __restrict__ bn_m, const float* __restrict__ bn_v,
    float* new_xyz, float* __restrict__ out, unsigned* ctrl) {
    __shared__ char smem[84000];
    const int t    = threadIdx.x;
    const int lane = t & 63;
    const int wid  = t >> 6;

    if (blockIdx.x < B_SZ) {
        // ================= FPS role (R7 body + watermark publish) =================
        float4* xyzw = (float4*)smem;
        unsigned long long (*red)[FPS_NW] = (unsigned long long (*)[FPS_NW])(smem + 65536);
        const int b = blockIdx.x;
        const float* base = xyz + (size_t)b * N_PTS * 3;

        v2f nX[8], nY[8], nZ[8], M[8];
        const float4* b4 = (const float4*)(base + (size_t)t * (FPS_PPT * 3));
        float4 v[12];
#pragma unroll
        for (int i = 0; i < 12; ++i) v[i] = b4[i];
        const float* vf = (const float*)v;
#pragma unroll
        for (int p = 0; p < 8; ++p) {
            float x0 = vf[(2 * p) * 3 + 0], x1 = vf[(2 * p + 1) * 3 + 0];
            float y0 = vf[(2 * p) * 3 + 1], y1 = vf[(2 * p + 1) * 3 + 1];
            float z0 = vf[(2 * p) * 3 + 2], z1 = vf[(2 * p + 1) * 3 + 2];
            nX[p] = (v2f){-x0, -x1};
            nY[p] = (v2f){-y0, -y1};
            nZ[p] = (v2f){-z0, -z1};
            M[p]  = (v2f){1e10f, 1e10f};
            int gi = t * FPS_PPT + 2 * p;
            xyzw[gi]     = (float4){x0, y0, z0, 0.0f};
            xyzw[gi + 1] = (float4){x1, y1, z1, 0.0f};
        }
        __syncthreads();

        float4 c4 = xyzw[0];
        float cx = c4.x, cy = c4.y, cz = c4.z;
        if (t == 0) {
            float* o = new_xyz + (size_t)b * NPOINT * 3;
            __hip_atomic_store(&o[0], cx, __ATOMIC_RELAXED, __HIP_MEMORY_SCOPE_AGENT);
            __hip_atomic_store(&o[1], cy, __ATOMIC_RELAXED, __HIP_MEMORY_SCOPE_AGENT);
            __hip_atomic_store(&o[2], cz, __ATOMIC_RELAXED, __HIP_MEMORY_SCOPE_AGENT);
        }

        for (int it = 1; it < NPOINT; ++it) {
            const v2f ccx = (v2f){cx, cx};
            const v2f ccy = (v2f){cy, cy};
            const v2f ccz = (v2f){cz, cz};
            int pb[8], pj[8];
#pragma unroll
            for (int p = 0; p < 8; ++p) {
                v2f dx = pk_add(nX[p], ccx);
                v2f dy = pk_add(nY[p], ccy);
                v2f dz = pk_add(nZ[p], ccz);
                v2f xx = pk_mul(dx, dx);
                v2f yy = pk_mul(dy, dy);
                v2f zz = pk_mul(dz, dz);
                v2f d  = pk_add(pk_add(xx, yy), zz);
                M[p].x = fminf(M[p].x, d.x);
                M[p].y = fminf(M[p].y, d.y);
                int bx = __float_as_int(M[p].x);
                int by = __float_as_int(M[p].y);
                bool g = by > bx;
                pb[p] = g ? by : bx;
                pj[p] = g ? (2 * p + 1) : (2 * p);
            }
            CMB(pb[0], pj[0], pb[1], pj[1]);
            CMB(pb[2], pj[2], pb[3], pj[3]);
            CMB(pb[4], pj[4], pb[5], pj[5]);
            CMB(pb[6], pj[6], pb[7], pj[7]);
            CMB(pb[0], pj[0], pb[2], pj[2]);
            CMB(pb[4], pj[4], pb[6], pj[6]);
            CMB(pb[0], pj[0], pb[4], pj[4]);
            int vb = pb[0];
            int vi = t * FPS_PPT + pj[0];
            DPP_ARGMAX(vb, vi, 0x111, 0xf);
            DPP_ARGMAX(vb, vi, 0x112, 0xf);
            DPP_ARGMAX(vb, vi, 0x114, 0xf);
            DPP_ARGMAX(vb, vi, 0x118, 0xf);
            DPP_ARGMAX(vb, vi, 0x142, 0xa);
            DPP_ARGMAX(vb, vi, 0x143, 0xc);
            if (lane == 63)
                red[it & 1][wid] = ((unsigned long long)(unsigned)vb << 32)
                                 | (unsigned)(N_PTS - 1 - vi);
            __syncthreads();
            const unsigned long long* rp = red[it & 1];
            unsigned long long k0 = rp[0], k1 = rp[1], k2 = rp[2], k3 = rp[3];
            unsigned long long b01 = k0 > k1 ? k0 : k1;
            unsigned long long b23 = k2 > k3 ? k2 : k3;
            unsigned long long best = b01 > b23 ? b01 : b23;
            const int idx = N_PTS - 1 - (int)(best & 0xFFFFull);
            float4 w4 = xyzw[idx];
            cx = w4.x; cy = w4.y; cz = w4.z;
            if (t == 0) {
                float* o = new_xyz + ((size_t)b * NPOINT + it) * 3;
                __hip_atomic_store(&o[0], cx, __ATOMIC_RELAXED, __HIP_MEMORY_SCOPE_AGENT);
                __hip_atomic_store(&o[1], cy, __ATOMIC_RELAXED, __HIP_MEMORY_SCOPE_AGENT);
                __hip_atomic_store(&o[2], cz, __ATOMIC_RELAXED, __HIP_MEMORY_SCOPE_AGENT);
                if ((it & 15) == 15)   // watermark: centers 0..it visible (release waits stores)
                    __hip_atomic_store(&ctrl[b], (unsigned)(it + 1),
                                       __ATOMIC_RELEASE, __HIP_MEMORY_SCOPE_AGENT);
            }
        }
        __syncthreads();   // LDS handoff to worker role
    }

    // ================= worker role (all 256 blocks; fps blocks join late) =================
    unsigned short (*Xh)[KPAD] = (unsigned short (*)[KPAD])smem;
    unsigned short (*Xl)[KPAD] = (unsigned short (*)[KPAD])(smem + 10752);
    float* sc_l = (float*)(smem + 21504);
    float* mn_l = (float*)(smem + 22032);
    float* bt_l = (float*)(smem + 22560);
    int*   idxs = (int*)(smem + 23088);
    float* nq   = (float*)(smem + 23216);
    int*   itsl = (int*)(smem + 23232);

    if (t < C_IN) {
        float g  = bn_g[t];
        float vv = bn_v[t] + 1e-5f;
        sc_l[t] = g / sqrtf(vv);
        mn_l[t] = bn_m[t];
        bt_l[t] = bn_b[t];
    }
    __syncthreads();

    for (;;) {
        if (t == 0) *itsl = (int)atomicAdd(&ctrl[8], 1u);   // dynamic claim: deadlock-free
        __syncthreads();
        const int item = *itsl;
        if (item >= NITEMS) break;
        const int s  = item >> 3;       // s ascending over claims -> matches fps production
        const int bb = item & 7;
        if (t == 0) {
            while ((int)__hip_atomic_load(&ctrl[bb], __ATOMIC_RELAXED,
                                          __HIP_MEMORY_SCOPE_AGENT) < s + 1)
                __builtin_amdgcn_s_sleep(16);
        }
        __syncthreads();

        // ---- ball query for (bb, s): wave 0, first NSAMPLE in index order ----
        if (wid == 0) {
            float* qp = new_xyz + ((size_t)bb * NPOINT + s) * 3;
            float qx = __hip_atomic_load(&qp[0], __ATOMIC_RELAXED, __HIP_MEMORY_SCOPE_AGENT);
            float qy = __hip_atomic_load(&qp[1], __ATOMIC_RELAXED, __HIP_MEMORY_SCOPE_AGENT);
            float qz = __hip_atomic_load(&qp[2], __ATOMIC_RELAXED, __HIP_MEMORY_SCOPE_AGENT);
            if (lane == 0) { nq[0] = qx; nq[1] = qy; nq[2] = qz; }
            const float* xb = xyz + (size_t)bb * N_PTS * 3;
            int total = 0, first = -1;
            const unsigned long long mlt = (1ull << lane) - 1ull;
            for (int ch = 0; ch < N_PTS / 64; ++ch) {
                int i2 = ch * 64 + lane;
                float x = xb[i2 * 3 + 0], y = xb[i2 * 3 + 1], z = xb[i2 * 3 + 2];
                float dx = qx - x, dy = qy - y, dz = qz - z;
                float d2 = ((dx * dx) + (dy * dy)) + (dz * dz);
                bool valid = d2 < R2;
                unsigned long long m = __ballot(valid);
                if (valid) {
                    int pos = total + __popcll(m & mlt);
                    if (pos < NSAMPLE) idxs[pos] = i2;
                }
                if (first < 0 && m != 0ull) first = ch * 64 + (__ffsll(m) - 1);
                total += __popcll(m);
                if (total >= NSAMPLE) break;
            }
            if (total < NSAMPLE) {
                if (lane >= total && lane < NSAMPLE) idxs[lane] = first;
            }
        }
        __syncthreads();

        // ---- stage x tile (bf16 hi/lo) ----
        {
            const int ks = t & 31;
            const int qh = t >> 5;
            const float* frow = feat + ((size_t)bb * N_PTS + idxs[ks]) * C_FEAT;
#pragma unroll
            for (int m2 = 0; m2 < 4; ++m2) {
                int qq = m2 * 8 + qh;
                int c0 = qq * 4;
                float4 f = *(const float4*)&frow[c0];
                float v0 = bn_relu(f.x, mn_l[3 + c0 + 0], sc_l[3 + c0 + 0], bt_l[3 + c0 + 0]);
                float v1 = bn_relu(f.y, mn_l[3 + c0 + 1], sc_l[3 + c0 + 1], bt_l[3 + c0 + 1]);
                float v2 = bn_relu(f.z, mn_l[3 + c0 + 2], sc_l[3 + c0 + 2], bt_l[3 + c0 + 2]);
                float v3 = bn_relu(f.w, mn_l[3 + c0 + 3], sc_l[3 + c0 + 3], bt_l[3 + c0 + 3]);
                unsigned short h0 = f2bf(v0), h1 = f2bf(v1), h2 = f2bf(v2), h3 = f2bf(v3);
                uint2 hv, lv;
                hv.x = (unsigned)h0 | ((unsigned)h1 << 16);
                hv.y = (unsigned)h2 | ((unsigned)h3 << 16);
                lv.x = (unsigned)f2bf(v0 - bf2f(h0)) | ((unsigned)f2bf(v1 - bf2f(h1)) << 16);
                lv.y = (unsigned)f2bf(v2 - bf2f(h2)) | ((unsigned)f2bf(v3 - bf2f(h3)) << 16);
                *(uint2*)&Xh[ks][c0] = hv;
                *(uint2*)&Xl[ks][c0] = lv;
            }
        }
        if (t < 32) {
            const int row = t;
            const int id  = idxs[row];
            const float* p = xyz + ((size_t)bb * N_PTS + id) * 3;
            uint4 z4 = {0u, 0u, 0u, 0u};
            uint4 hh = z4, ll = z4;
            unsigned short h[3];
#pragma unroll
            for (int d = 0; d < 3; ++d) {
                float g = p[d] - nq[d];
                float vv = bn_relu(g, mn_l[d], sc_l[d], bt_l[d]);
                h[d] = f2bf(vv);
                unsigned short lo = f2bf(vv - bf2f(h[d]));
                if (d == 0) { hh.x |= h[d];                 ll.x |= lo; }
                if (d == 1) { hh.x |= (unsigned)h[d] << 16; ll.x |= (unsigned)lo << 16; }
                if (d == 2) { hh.y |= h[d];                 ll.y |= lo; }
            }
            *(uint4*)&Xh[row][128] = hh;  *(uint4*)&Xl[row][128] = ll;
            *(uint4*)&Xh[row][136] = z4;  *(uint4*)&Xl[row][136] = z4;
            *(uint4*)&Xh[row][144] = z4;  *(uint4*)&Xl[row][144] = z4;
            *(uint4*)&Xh[row][152] = z4;  *(uint4*)&Xl[row][152] = z4;
            *(uint4*)&Xh[row][160] = z4;  *(uint4*)&Xl[row][160] = z4;
        }
        __syncthreads();

        // ---- split-bf16 MFMA GEMM + max epilogue ----
        f32x4 zero = {0.f, 0.f, 0.f, 0.f};
        f32x4 acc[2][4];
#pragma unroll
        for (int m2 = 0; m2 < 2; ++m2)
#pragma unroll
            for (int n = 0; n < 4; ++n) acc[m2][n] = zero;

        const int r0 = lane & 15;
#pragma unroll
        for (int kt = 0; kt < KT; ++kt) {
            const int k0 = kt * 32 + (lane >> 4) * 8;
            bf16x8 a0h = *(const bf16x8*)&Xh[r0][k0];
            bf16x8 a1h = *(const bf16x8*)&Xh[16 + r0][k0];
            bf16x8 a0l = *(const bf16x8*)&Xl[r0][k0];
            bf16x8 a1l = *(const bf16x8*)&Xl[16 + r0][k0];
#pragma unroll
            for (int n = 0; n < 4; ++n) {
                const int nt = wid * 4 + n;
                const size_t off = (((size_t)kt * NT + nt) * 64 + lane) * 8;
                bf16x8 bh = *(const bf16x8*)&Wb_hi[off];
                bf16x8 bl = *(const bf16x8*)&Wb_lo[off];
                acc[0][n] = __builtin_amdgcn_mfma_f32_16x16x32_bf16(a0h, bh, acc[0][n], 0, 0, 0);
                acc[1][n] = __builtin_amdgcn_mfma_f32_16x16x32_bf16(a1h, bh, acc[1][n], 0, 0, 0);
                acc[0][n] = __builtin_amdgcn_mfma_f32_16x16x32_bf16(a0l, bh, acc[0][n], 0, 0, 0);
                acc[1][n] = __builtin_amdgcn_mfma_f32_16x16x32_bf16(a1l, bh, acc[1][n], 0, 0, 0);
                acc[0][n] = __builtin_amdgcn_mfma_f32_16x16x32_bf16(a0h, bl, acc[0][n], 0, 0, 0);
                acc[1][n] = __builtin_amdgcn_mfma_f32_16x16x32_bf16(a1h, bl, acc[1][n], 0, 0, 0);
            }
        }

#pragma unroll
        for (int n = 0; n < 4; ++n) {
            float m0 = fmaxf(acc[0][n][0], acc[1][n][0]);
            float m1 = fmaxf(acc[0][n][1], acc[1][n][1]);
            float m2 = fmaxf(acc[0][n][2], acc[1][n][2]);
            float m3 = fmaxf(acc[0][n][3], acc[1][n][3]);
            float pm = fmaxf(fmaxf(m0, m1), fmaxf(m2, m3));
            pm = fmaxf(pm, __shfl_xor(pm, 16));
            pm = fmaxf(pm, __shfl_xor(pm, 32));
            if (lane < 16) {
                int o = (wid * 4 + n) * 16 + lane;
                out[(size_t)bb * C_OUT * NPOINT + (size_t)o * NPOINT + s] = pm + bias[o];
            }
        }
        // next claim's barrier protects LDS reuse
    }
}

extern "C" void kernel_launch(void* const* d_in, const int* in_sizes, int n_in,
                              void* d_out, int out_size, void* d_ws, size_t ws_size,
                              hipStream_t stream) {
    const float* xyz  = (const float*)d_in[0];
    const float* feat = (const float*)d_in[1];
    const float* W    = (const float*)d_in[2];
    const float* bias = (const float*)d_in[3];
    const float* bn_g = (const float*)d_in[4];
    const float* bn_b = (const float*)d_in[5];
    const float* bn_m = (const float*)d_in[6];
    const float* bn_v = (const float*)d_in[7];

    float* new_xyz  = (float*)d_out;                                   // (8,1024,3)
    float* out_feat = (float*)d_out + (size_t)B_SZ * NPOINT * 3;       // (8,256,1024)

    unsigned short* Wb_hi = (unsigned short*)d_ws;                     // 81920 B
    unsigned short* Wb_lo = Wb_hi + (size_t)KT * NT * 64 * 8;          // 81920 B
    unsigned*       ctrl  = (unsigned*)((char*)d_ws + 163840);         // flags[8] + cursor

    hipLaunchKernelGGL(k_zero,   dim3(1),       dim3(64), 0, stream, ctrl);
    hipLaunchKernelGGL(k_wtrans, dim3(KT * NT), dim3(64), 0, stream, W, Wb_hi, Wb_lo);
    hipLaunchKernelGGL(k_mega,   dim3(256),     dim3(256), 0, stream,
                       xyz, feat, Wb_hi, Wb_lo, bias,
                       bn_g, bn_b, bn_m, bn_v, new_xyz, out_feat, ctrl);
}

// Round 9
// 770.289 us; speedup vs baseline: 1.1660x; 1.0028x over previous
//
#pragma clang fp contract(off)
#include <hip/hip_runtime.h>
#include <math.h>

#define N_PTS   4096
#define B_SZ    8
#define NPOINT  1024
#define NSAMPLE 32
#define C_FEAT  128
#define C_IN    131
#define C_OUT   256
#define R2      1e-2f   // float(0.1*0.1) as JAX weak-casts it

#define KT      5       // K tiles of 32 (131 -> 160 padded)
#define NT      16      // N tiles of 16 (256)
#define KPAD    168     // LDS row stride in bf16 elems
#define NITEMS  (B_SZ * NPOINT)   // one item = one (b, s)

typedef __attribute__((ext_vector_type(8))) short bf16x8;
typedef __attribute__((ext_vector_type(4))) float f32x4;
typedef __attribute__((ext_vector_type(2))) float v2f;

__device__ __forceinline__ unsigned short f2bf(float f) {   // RNE, matches hw cvt
    unsigned u = __float_as_uint(f);
    return (unsigned short)((u + 0x7FFF + ((u >> 16) & 1)) >> 16);
}
__device__ __forceinline__ float bf2f(unsigned short h) {
    return __uint_as_float(((unsigned)h) << 16);
}

// forced VOP3P packed fp32 (full-rate on CDNA4)
__device__ __forceinline__ v2f pk_add(v2f a, v2f b) {
    v2f d; asm("v_pk_add_f32 %0, %1, %2" : "=v"(d) : "v"(a), "v"(b)); return d;
}
__device__ __forceinline__ v2f pk_mul(v2f a, v2f b) {
    v2f d; asm("v_pk_mul_f32 %0, %1, %2" : "=v"(d) : "v"(a), "v"(b)); return d;
}

// ---------------- K0: W split/swizzle + ctrl zeroing (folded; stream-ordered before mega) ----
__global__ __launch_bounds__(64) void k_wtrans(const float* __restrict__ W,
                                               unsigned short* __restrict__ Wb_hi,
                                               unsigned short* __restrict__ Wb_lo,
                                               unsigned* __restrict__ ctrl) {
    if (blockIdx.x == 0 && threadIdx.x < 16) ctrl[threadIdx.x] = 0u;
    const int blk  = blockIdx.x;            // kt*NT + nt
    const int kt   = blk / NT, nt = blk % NT;
    const int lane = threadIdx.x;
    const int o    = nt * 16 + (lane & 15);
    const int k0   = kt * 32 + (lane >> 4) * 8;
    const size_t base = ((size_t)blk * 64 + lane) * 8;
#pragma unroll
    for (int j = 0; j < 8; ++j) {
        int k = k0 + j;
        float v = 0.0f;
        if (k < C_IN) {
            int src = (k < C_FEAT) ? (k + 3) : (k - C_FEAT);
            v = W[o * C_IN + src];
        }
        unsigned short hh = f2bf(v);
        Wb_hi[base + j] = hh;
        Wb_lo[base + j] = f2bf(v - bf2f(hh));
    }
}

// ---------------- FPS helpers (R7-proven) ----------------
#define FPS_BLOCK 256
#define FPS_PPT   16    // 8 float2 pairs per thread
#define FPS_NW    (FPS_BLOCK / 64)

#define DPP_ARGMAX(vb, vi, ctrl_, rmask)                                          \
    do {                                                                          \
        int _nb = __builtin_amdgcn_update_dpp(vb, vb, ctrl_, rmask, 0xf, false);  \
        int _ni = __builtin_amdgcn_update_dpp(vi, vi, ctrl_, rmask, 0xf, false);  \
        bool _g = (_nb >= vb);                                                    \
        vb = _g ? _nb : vb;                                                       \
        vi = _g ? _ni : vi;                                                       \
    } while (0)

#define CMB(ab, aj, bb_, bj_)                                                     \
    do {                                                                          \
        bool _g = ((bb_) > (ab));                                                 \
        ab = _g ? (bb_) : (ab);                                                   \
        aj = _g ? (bj_) : (aj);                                                   \
    } while (0)

__device__ __forceinline__ float bn_relu(float v, float mean, float scale, float beta) {
    float r = ((v - mean) * scale) + beta;
    return fmaxf(r, 0.0f);
}

// ---------------- MEGA kernel: fps (blocks 0-7) + pipelined bq+gemm workers ----------------
// smem layout (union by role):
//   fps:    xyzw float4[4096] @0 (65536), red u64[2][4] @65536
//   worker: Xh @0 (10752), Xl @10752, sc @21504, mn @22032, bt @22560,
//           idxs @23088 (32 int), nq @23216 (3 f), item @23232 (int)
// 84000 B total -> 1 block/CU (no worker co-resident with an fps block).
__global__ __launch_bounds__(256) void k_mega(
    const float* __restrict__ xyz, const float* __restrict__ feat,
    const unsigned short* __restrict__ Wb_hi, const unsigned short* __restrict__ Wb_lo,
    const float* __restrict__ bias,
    const float* __restrict__ bn_g, const float* __restrict__ bn_b,
    const float* __restrict__ bn_m, const float* __restrict__ bn_v,
    float* new_xyz, float* __restrict__ out, unsigned* ctrl) {
    __shared__ char smem[84000];
    const int t    = threadIdx.x;
    const int lane = t & 63;
    const int wid  = t >> 6;

    if (blockIdx.x < B_SZ) {
        // ================= FPS role (R7 body + windowed center flush) =================
        float4* xyzw = (float4*)smem;
        unsigned long long (*red)[FPS_NW] = (unsigned long long (*)[FPS_NW])(smem + 65536);
        const int b = blockIdx.x;
        const float* base = xyz + (size_t)b * N_PTS * 3;

        v2f nX[8], nY[8], nZ[8], M[8];
        const float4* b4 = (const float4*)(base + (size_t)t * (FPS_PPT * 3));
        float4 v[12];
#pragma unroll
        for (int i = 0; i < 12; ++i) v[i] = b4[i];
        const float* vf = (const float*)v;
#pragma unroll
        for (int p = 0; p < 8; ++p) {
            float x0 = vf[(2 * p) * 3 + 0], x1 = vf[(2 * p + 1) * 3 + 0];
            float y0 = vf[(2 * p) * 3 + 1], y1 = vf[(2 * p + 1) * 3 + 1];
            float z0 = vf[(2 * p) * 3 + 2], z1 = vf[(2 * p + 1) * 3 + 2];
            nX[p] = (v2f){-x0, -x1};
            nY[p] = (v2f){-y0, -y1};
            nZ[p] = (v2f){-z0, -z1};
            M[p]  = (v2f){1e10f, 1e10f};
            int gi = t * FPS_PPT + 2 * p;
            xyzw[gi]     = (float4){x0, y0, z0, 0.0f};
            xyzw[gi + 1] = (float4){x1, y1, z1, 0.0f};
        }
        __syncthreads();

        float4 c4 = xyzw[0];
        float cx = c4.x, cy = c4.y, cz = c4.z;
        int myidx = 0;   // window-slot center capture (t0 holds s=0 = point 0)

        for (int it = 1; it < NPOINT; ++it) {
            const v2f ccx = (v2f){cx, cx};
            const v2f ccy = (v2f){cy, cy};
            const v2f ccz = (v2f){cz, cz};
            int pb[8], pj[8];
#pragma unroll
            for (int p = 0; p < 8; ++p) {
                v2f dx = pk_add(nX[p], ccx);
                v2f dy = pk_add(nY[p], ccy);
                v2f dz = pk_add(nZ[p], ccz);
                v2f xx = pk_mul(dx, dx);
                v2f yy = pk_mul(dy, dy);
                v2f zz = pk_mul(dz, dz);
                v2f d  = pk_add(pk_add(xx, yy), zz);
                M[p].x = fminf(M[p].x, d.x);
                M[p].y = fminf(M[p].y, d.y);
                int bx = __float_as_int(M[p].x);
                int by = __float_as_int(M[p].y);
                bool g = by > bx;
                pb[p] = g ? by : bx;
                pj[p] = g ? (2 * p + 1) : (2 * p);
            }
            CMB(pb[0], pj[0], pb[1], pj[1]);
            CMB(pb[2], pj[2], pb[3], pj[3]);
            CMB(pb[4], pj[4], pb[5], pj[5]);
            CMB(pb[6], pj[6], pb[7], pj[7]);
            CMB(pb[0], pj[0], pb[2], pj[2]);
            CMB(pb[4], pj[4], pb[6], pj[6]);
            CMB(pb[0], pj[0], pb[4], pj[4]);
            int vb = pb[0];
            int vi = t * FPS_PPT + pj[0];
            DPP_ARGMAX(vb, vi, 0x111, 0xf);
            DPP_ARGMAX(vb, vi, 0x112, 0xf);
            DPP_ARGMAX(vb, vi, 0x114, 0xf);
            DPP_ARGMAX(vb, vi, 0x118, 0xf);
            DPP_ARGMAX(vb, vi, 0x142, 0xa);
            DPP_ARGMAX(vb, vi, 0x143, 0xc);
            if (lane == 63)
                red[it & 1][wid] = ((unsigned long long)(unsigned)vb << 32)
                                 | (unsigned)(N_PTS - 1 - vi);
            __syncthreads();   // also drains last window's flush stores (all waves)
            // watermark publish: t0 has no pending stores here -> release drain is free
            if ((it & 15) == 0 && t == 0)
                __hip_atomic_store(&ctrl[b], (unsigned)it,
                                   __ATOMIC_RELEASE, __HIP_MEMORY_SCOPE_AGENT);
            const unsigned long long* rp = red[it & 1];
            unsigned long long k0 = rp[0], k1 = rp[1], k2 = rp[2], k3 = rp[3];
            unsigned long long b01 = k0 > k1 ? k0 : k1;
            unsigned long long b23 = k2 > k3 ? k2 : k3;
            unsigned long long best = b01 > b23 ? b01 : b23;
            const int idx = N_PTS - 1 - (int)(best & 0xFFFFull);
            float4 w4 = xyzw[idx];
            cx = w4.x; cy = w4.y; cz = w4.z;
            if (t == (it & 15)) myidx = idx;          // register capture, no LDS/global
            if ((it & 15) == 15 && t < 16) {          // issue 16 centers; drained next barrier
                float4 w = xyzw[myidx];
                float* o = new_xyz + ((size_t)b * NPOINT + (it - 15) + t) * 3;
                __hip_atomic_store(&o[0], w.x, __ATOMIC_RELAXED, __HIP_MEMORY_SCOPE_AGENT);
                __hip_atomic_store(&o[1], w.y, __ATOMIC_RELAXED, __HIP_MEMORY_SCOPE_AGENT);
                __hip_atomic_store(&o[2], w.z, __ATOMIC_RELAXED, __HIP_MEMORY_SCOPE_AGENT);
            }
        }
        __syncthreads();   // drains s=1008..1023 stores + LDS handoff to worker role
        if (t == 0)
            __hip_atomic_store(&ctrl[b], (unsigned)NPOINT,
                               __ATOMIC_RELEASE, __HIP_MEMORY_SCOPE_AGENT);
    }

    // ================= worker role (all 256 blocks; fps blocks join late) =================
    unsigned short (*Xh)[KPAD] = (unsigned short (*)[KPAD])smem;
    unsigned short (*Xl)[KPAD] = (unsigned short (*)[KPAD])(smem + 10752);
    float* sc_l = (float*)(smem + 21504);
    float* mn_l = (float*)(smem + 22032);
    float* bt_l = (float*)(smem + 22560);
    int*   idxs = (int*)(smem + 23088);
    float* nq   = (float*)(smem + 23216);
    int*   itsl = (int*)(smem + 23232);

    if (t < C_IN) {
        float g  = bn_g[t];
        float vv = bn_v[t] + 1e-5f;
        sc_l[t] = g / sqrtf(vv);
        mn_l[t] = bn_m[t];
        bt_l[t] = bn_b[t];
    }
    __syncthreads();

    for (;;) {
        if (t == 0) *itsl = (int)atomicAdd(&ctrl[8], 1u);   // dynamic claim: deadlock-free
        __syncthreads();
        const int item = *itsl;
        if (item >= NITEMS) break;
        const int s  = item >> 3;       // s ascending over claims -> matches fps production
        const int bb = item & 7;
        if (t == 0) {
            while ((int)__hip_atomic_load(&ctrl[bb], __ATOMIC_RELAXED,
                                          __HIP_MEMORY_SCOPE_AGENT) < s + 1)
                __builtin_amdgcn_s_sleep(32);
        }
        __syncthreads();

        // ---- ball query for (bb, s): wave 0, first NSAMPLE in index order ----
        if (wid == 0) {
            float* qp = new_xyz + ((size_t)bb * NPOINT + s) * 3;
            float qx = __hip_atomic_load(&qp[0], __ATOMIC_RELAXED, __HIP_MEMORY_SCOPE_AGENT);
            float qy = __hip_atomic_load(&qp[1], __ATOMIC_RELAXED, __HIP_MEMORY_SCOPE_AGENT);
            float qz = __hip_atomic_load(&qp[2], __ATOMIC_RELAXED, __HIP_MEMORY_SCOPE_AGENT);
            if (lane == 0) { nq[0] = qx; nq[1] = qy; nq[2] = qz; }
            const float* xb = xyz + (size_t)bb * N_PTS * 3;
            int total = 0, first = -1;
            const unsigned long long mlt = (1ull << lane) - 1ull;
            for (int ch = 0; ch < N_PTS / 64; ++ch) {
                int i2 = ch * 64 + lane;
                float x = xb[i2 * 3 + 0], y = xb[i2 * 3 + 1], z = xb[i2 * 3 + 2];
                float dx = qx - x, dy = qy - y, dz = qz - z;
                float d2 = ((dx * dx) + (dy * dy)) + (dz * dz);
                bool valid = d2 < R2;
                unsigned long long m = __ballot(valid);
                if (valid) {
                    int pos = total + __popcll(m & mlt);
                    if (pos < NSAMPLE) idxs[pos] = i2;
                }
                if (first < 0 && m != 0ull) first = ch * 64 + (__ffsll(m) - 1);
                total += __popcll(m);
                if (total >= NSAMPLE) break;
            }
            if (total < NSAMPLE) {
                if (lane >= total && lane < NSAMPLE) idxs[lane] = first;
            }
        }
        __syncthreads();

        // ---- stage x tile (bf16 hi/lo) ----
        {
            const int ks = t & 31;
            const int qh = t >> 5;
            const float* frow = feat + ((size_t)bb * N_PTS + idxs[ks]) * C_FEAT;
#pragma unroll
            for (int m2 = 0; m2 < 4; ++m2) {
                int qq = m2 * 8 + qh;
                int c0 = qq * 4;
                float4 f = *(const float4*)&frow[c0];
                float v0 = bn_relu(f.x, mn_l[3 + c0 + 0], sc_l[3 + c0 + 0], bt_l[3 + c0 + 0]);
                float v1 = bn_relu(f.y, mn_l[3 + c0 + 1], sc_l[3 + c0 + 1], bt_l[3 + c0 + 1]);
                float v2 = bn_relu(f.z, mn_l[3 + c0 + 2], sc_l[3 + c0 + 2], bt_l[3 + c0 + 2]);
                float v3 = bn_relu(f.w, mn_l[3 + c0 + 3], sc_l[3 + c0 + 3], bt_l[3 + c0 + 3]);
                unsigned short h0 = f2bf(v0), h1 = f2bf(v1), h2 = f2bf(v2), h3 = f2bf(v3);
                uint2 hv, lv;
                hv.x = (unsigned)h0 | ((unsigned)h1 << 16);
                hv.y = (unsigned)h2 | ((unsigned)h3 << 16);
                lv.x = (unsigned)f2bf(v0 - bf2f(h0)) | ((unsigned)f2bf(v1 - bf2f(h1)) << 16);
                lv.y = (unsigned)f2bf(v2 - bf2f(h2)) | ((unsigned)f2bf(v3 - bf2f(h3)) << 16);
                *(uint2*)&Xh[ks][c0] = hv;
                *(uint2*)&Xl[ks][c0] = lv;
            }
        }
        if (t < 32) {
            const int row = t;
            const int id  = idxs[row];
            const float* p = xyz + ((size_t)bb * N_PTS + id) * 3;
            uint4 z4 = {0u, 0u, 0u, 0u};
            uint4 hh = z4, ll = z4;
            unsigned short h[3];
#pragma unroll
            for (int d = 0; d < 3; ++d) {
                float g = p[d] - nq[d];
                float vv = bn_relu(g, mn_l[d], sc_l[d], bt_l[d]);
                h[d] = f2bf(vv);
                unsigned short lo = f2bf(vv - bf2f(h[d]));
                if (d == 0) { hh.x |= h[d];                 ll.x |= lo; }
                if (d == 1) { hh.x |= (unsigned)h[d] << 16; ll.x |= (unsigned)lo << 16; }
                if (d == 2) { hh.y |= h[d];                 ll.y |= lo; }
            }
            *(uint4*)&Xh[row][128] = hh;  *(uint4*)&Xl[row][128] = ll;
            *(uint4*)&Xh[row][136] = z4;  *(uint4*)&Xl[row][136] = z4;
            *(uint4*)&Xh[row][144] = z4;  *(uint4*)&Xl[row][144] = z4;
            *(uint4*)&Xh[row][152] = z4;  *(uint4*)&Xl[row][152] = z4;
            *(uint4*)&Xh[row][160] = z4;  *(uint4*)&Xl[row][160] = z4;
        }
        __syncthreads();

        // ---- split-bf16 MFMA GEMM + max epilogue ----
        f32x4 zero = {0.f, 0.f, 0.f, 0.f};
        f32x4 acc[2][4];
#pragma unroll
        for (int m2 = 0; m2 < 2; ++m2)
#pragma unroll
            for (int n = 0; n < 4; ++n) acc[m2][n] = zero;

        const int r0 = lane & 15;
#pragma unroll
        for (int kt = 0; kt < KT; ++kt) {
            const int k0 = kt * 32 + (lane >> 4) * 8;
            bf16x8 a0h = *(const bf16x8*)&Xh[r0][k0];
            bf16x8 a1h = *(const bf16x8*)&Xh[16 + r0][k0];
            bf16x8 a0l = *(const bf16x8*)&Xl[r0][k0];
            bf16x8 a1l = *(const bf16x8*)&Xl[16 + r0][k0];
#pragma unroll
            for (int n = 0; n < 4; ++n) {
                const int nt = wid * 4 + n;
                const size_t off = (((size_t)kt * NT + nt) * 64 + lane) * 8;
                bf16x8 bh = *(const bf16x8*)&Wb_hi[off];
                bf16x8 bl = *(const bf16x8*)&Wb_lo[off];
                acc[0][n] = __builtin_amdgcn_mfma_f32_16x16x32_bf16(a0h, bh, acc[0][n], 0, 0, 0);
                acc[1][n] = __builtin_amdgcn_mfma_f32_16x16x32_bf16(a1h, bh, acc[1][n], 0, 0, 0);
                acc[0][n] = __builtin_amdgcn_mfma_f32_16x16x32_bf16(a0l, bh, acc[0][n], 0, 0, 0);
                acc[1][n] = __builtin_amdgcn_mfma_f32_16x16x32_bf16(a1l, bh, acc[1][n], 0, 0, 0);
                acc[0][n] = __builtin_amdgcn_mfma_f32_16x16x32_bf16(a0h, bl, acc[0][n], 0, 0, 0);
                acc[1][n] = __builtin_amdgcn_mfma_f32_16x16x32_bf16(a1h, bl, acc[1][n], 0, 0, 0);
            }
        }

#pragma unroll
        for (int n = 0; n < 4; ++n) {
            float m0 = fmaxf(acc[0][n][0], acc[1][n][0]);
            float m1 = fmaxf(acc[0][n][1], acc[1][n][1]);
            float m2 = fmaxf(acc[0][n][2], acc[1][n][2]);
            float m3 = fmaxf(acc[0][n][3], acc[1][n][3]);
            float pm = fmaxf(fmaxf(m0, m1), fmaxf(m2, m3));
            pm = fmaxf(pm, __shfl_xor(pm, 16));
            pm = fmaxf(pm, __shfl_xor(pm, 32));
            if (lane < 16) {
                int o = (wid * 4 + n) * 16 + lane;
                out[(size_t)bb * C_OUT * NPOINT + (size_t)o * NPOINT + s] = pm + bias[o];
            }
        }
        // next claim's barrier protects LDS reuse
    }
}

extern "C" void kernel_launch(void* const* d_in, const int* in_sizes, int n_in,
                              void* d_out, int out_size, void* d_ws, size_t ws_size,
                              hipStream_t stream) {
    const float* xyz  = (const float*)d_in[0];
    const float* feat = (const float*)d_in[1];
    const float* W    = (const float*)d_in[2];
    const float* bias = (const float*)d_in[3];
    const float* bn_g = (const float*)d_in[4];
    const float* bn_b = (const float*)d_in[5];
    const float* bn_m = (const float*)d_in[6];
    const float* bn_v = (const float*)d_in[7];

    float* new_xyz  = (float*)d_out;                                   // (8,1024,3)
    float* out_feat = (float*)d_out + (size_t)B_SZ * NPOINT * 3;       // (8,256,1024)

    unsigned short* Wb_hi = (unsigned short*)d_ws;                     // 81920 B
    unsigned short* Wb_lo = Wb_hi + (size_t)KT * NT * 64 * 8;          // 81920 B
    unsigned*       ctrl  = (unsigned*)((char*)d_ws + 163840);         // flags[8] + cursor

    hipLaunchKernelGGL(k_wtrans, dim3(KT * NT), dim3(64), 0, stream, W, Wb_hi, Wb_lo, ctrl);
    hipLaunchKernelGGL(k_mega,   dim3(256),     dim3(256), 0, stream,
                       xyz, feat, Wb_hi, Wb_lo, bias,
                       bn_g, bn_b, bn_m, bn_v, new_xyz, out_feat, ctrl);
}